// Round 1
// baseline (3775.142 us; speedup 1.0000x reference)
//
#include <hip/hip_runtime.h>
#include <hip/hip_bf16.h>

#define DMODEL 1024
#define NH     16
#define DK     64
#define DV     64
#define BB     4
#define TT     2048
#define BT     (BB * TT)   // 8192

// ---------------------------------------------------------------------------
// fp32 tiled GEMM: C = A(8192x1024) * Bw(1024x1024)  (vector ALU, no fp32 MFMA)
// tile 128x128, 256 threads, per-thread 8x8, K-step 16.
// mode 0: proj layout  out[((b*NH+h)*TT + t)*64 + d]
// mode 1: proj layout + sigmoid(val + bias[n])
// mode 2: plain row-major out[m*1024 + n]
// ---------------------------------------------------------------------------
__global__ __launch_bounds__(256) void gemm_kernel(
    const float* __restrict__ A,
    const float* __restrict__ Bw,
    const float* __restrict__ bias,
    float* __restrict__ out,
    int mode)
{
    __shared__ __align__(16) float As[16][132];   // [k][m] transposed
    __shared__ __align__(16) float Bs[16][132];   // [k][n]

    const int tid = threadIdx.x;
    const int tm = tid >> 4;          // 0..15
    const int tn = tid & 15;          // 0..15
    const int m0 = blockIdx.x * 128;
    const int n0 = blockIdx.y * 128;

    float acc[8][8];
#pragma unroll
    for (int i = 0; i < 8; ++i)
#pragma unroll
        for (int j = 0; j < 8; ++j) acc[i][j] = 0.f;

    const int arow = tid >> 2;         // 0..63
    const int akq  = (tid & 3) * 4;    // 0,4,8,12
    const int brow = tid >> 5;         // 0..7
    const int bnq  = (tid & 31) * 4;   // 0..124

    for (int k0 = 0; k0 < 1024; k0 += 16) {
#pragma unroll
        for (int it = 0; it < 2; ++it) {
            const int mr = it * 64 + arow;
            const float4 va = *(const float4*)(A + (size_t)(m0 + mr) * 1024 + k0 + akq);
            As[akq + 0][mr] = va.x;
            As[akq + 1][mr] = va.y;
            As[akq + 2][mr] = va.z;
            As[akq + 3][mr] = va.w;
        }
#pragma unroll
        for (int it = 0; it < 2; ++it) {
            const int kr = it * 8 + brow;
            const float4 vb = *(const float4*)(Bw + (size_t)(k0 + kr) * 1024 + n0 + bnq);
            *(float4*)&Bs[kr][bnq] = vb;
        }
        __syncthreads();
#pragma unroll
        for (int k = 0; k < 16; ++k) {
            float a[8], b[8];
            *(float4*)&a[0] = *(const float4*)&As[k][tm * 8];
            *(float4*)&a[4] = *(const float4*)&As[k][tm * 8 + 4];
            *(float4*)&b[0] = *(const float4*)&Bs[k][tn * 8];
            *(float4*)&b[4] = *(const float4*)&Bs[k][tn * 8 + 4];
#pragma unroll
            for (int i = 0; i < 8; ++i)
#pragma unroll
                for (int j = 0; j < 8; ++j)
                    acc[i][j] = fmaf(a[i], b[j], acc[i][j]);
        }
        __syncthreads();
    }

    if (mode == 2) {
#pragma unroll
        for (int i = 0; i < 8; ++i) {
            const int m = m0 + tm * 8 + i;
            float* dst = out + (size_t)m * 1024 + n0 + tn * 8;
            *(float4*)dst       = make_float4(acc[i][0], acc[i][1], acc[i][2], acc[i][3]);
            *((float4*)dst + 1) = make_float4(acc[i][4], acc[i][5], acc[i][6], acc[i][7]);
        }
    } else {
        const int nn = n0 + tn * 8;
        const int h = nn >> 6;
        const int d = nn & 63;
        float bb[8];
        if (mode == 1) {
#pragma unroll
            for (int j = 0; j < 8; ++j) bb[j] = bias[nn + j];
        }
#pragma unroll
        for (int i = 0; i < 8; ++i) {
            const int m  = m0 + tm * 8 + i;
            const int b_ = m >> 11;       // m / 2048
            const int t_ = m & 2047;
            float v[8];
#pragma unroll
            for (int j = 0; j < 8; ++j) {
                float x = acc[i][j];
                if (mode == 1) x = 1.f / (1.f + expf(-(x + bb[j])));
                v[j] = x;
            }
            float* dst = out + ((size_t)((b_ * NH + h) * TT + t_) << 6) + d;
            *(float4*)dst       = make_float4(v[0], v[1], v[2], v[3]);
            *((float4*)dst + 1) = make_float4(v[4], v[5], v[6], v[7]);
        }
    }
}

// ---------------------------------------------------------------------------
// Sequential gated scan. One block per (b,h) chain. 256 threads.
// tid = c*4 + r4 : thread owns column c (0..63), rows [16*r4, 16*r4+16)
// of S_K, C_QV, G (16 regs each). Output uses the identity
//   o_t = (q^T S_K) C_QV - q^T G   (avoids the 64^3 S_K@C_QV matmul).
// ---------------------------------------------------------------------------
__global__ __launch_bounds__(256) void scan_kernel(
    const float* __restrict__ Q,  const float* __restrict__ Kv,
    const float* __restrict__ V,  const float* __restrict__ AK,
    const float* __restrict__ AC, float* __restrict__ Oflat)
{
    const int bh  = blockIdx.x;          // b*NH + h
    const int b_  = bh >> 4;
    const int h_  = bh & 15;
    const int tid = threadIdx.x;
    const int c   = tid >> 2;            // column 0..63
    const int r4  = tid & 3;             // row quarter
    const int i0  = r4 * 16;

    __shared__ __align__(16) float vals[2][5][64];  // q,k,v,aK,aC per step
    __shared__ __align__(16) float u_lds[64];

    const size_t base = (size_t)bh * TT * 64;
    const float* arrs[5] = {Q + base, Kv + base, V + base, AK + base, AC + base};

    float sk[16], cv[16], g[16];
#pragma unroll
    for (int r = 0; r < 16; ++r) { sk[r] = 0.f; cv[r] = 0.f; g[r] = 0.f; }

    const bool loader = (tid < 80);
    const int  larr = tid >> 4;          // 0..4 (valid when loader)
    const int  loff = (tid & 15) * 4;    // 0..60
    float4 pf[2];

    if (loader) {
        pf[0] = *(const float4*)(arrs[larr] + 0 * 64 + loff);
        pf[1] = *(const float4*)(arrs[larr] + 1 * 64 + loff);
        *(float4*)&vals[0][larr][loff] = pf[0];
    }
    __syncthreads();

    for (int t = 0; t < TT; ++t) {
        const int cur = t & 1;
        // distance-2 prefetch: issue load of t+2 into the freed register set
        if (loader && (t + 2) < TT) {
            pf[cur] = *(const float4*)(arrs[larr] + (size_t)(t + 2) * 64 + loff);
        }

        float qv[16], kv[16], ak[16], ac[16];
#pragma unroll
        for (int r = 0; r < 16; r += 4) {
            *(float4*)&qv[r] = *(const float4*)&vals[cur][0][i0 + r];
            *(float4*)&kv[r] = *(const float4*)&vals[cur][1][i0 + r];
            *(float4*)&ak[r] = *(const float4*)&vals[cur][3][i0 + r];
            *(float4*)&ac[r] = *(const float4*)&vals[cur][4][i0 + r];
        }
        const float vc  = vals[cur][2][c];
        const float kc  = vals[cur][1][c];
        const float akc = vals[cur][3][c];

        // ktC partial (uses aC-scaled OLD C_QV) + C_QV update
        float pk[4] = {0.f, 0.f, 0.f, 0.f};
#pragma unroll
        for (int r = 0; r < 16; ++r) {
            const float s = ac[r] * cv[r];
            pk[r & 3] = fmaf(kv[r], s, pk[r & 3]);
            cv[r] = fmaf(qv[r], vc, s);      // C_QV_new = aC*C_QV + q (x) v
        }
        float ktc = (pk[0] + pk[1]) + (pk[2] + pk[3]);
        ktc += __shfl_xor(ktc, 1);
        ktc += __shfl_xor(ktc, 2);

        // G, S_K updates + u = q^T S_K, w = q^T G partials
        float pu[4] = {0.f, 0.f, 0.f, 0.f};
        float pw[4] = {0.f, 0.f, 0.f, 0.f};
#pragma unroll
        for (int r = 0; r < 16; ++r) {
            g[r]  = fmaf(ak[r], g[r], kv[r] * ktc);
            sk[r] = fmaf(ak[r] * akc, sk[r], kv[r] * kc);
            pu[r & 3] = fmaf(qv[r], sk[r], pu[r & 3]);
            pw[r & 3] = fmaf(qv[r], g[r],  pw[r & 3]);
        }
        float u = (pu[0] + pu[1]) + (pu[2] + pu[3]);
        u += __shfl_xor(u, 1);
        u += __shfl_xor(u, 2);
        float w = (pw[0] + pw[1]) + (pw[2] + pw[3]);
        w += __shfl_xor(w, 1);
        w += __shfl_xor(w, 2);

        if (r4 == 0) u_lds[c] = u;
        __syncthreads();

        // o[c] = sum_j u[j] * C_QV[j][c]
        float po[4] = {0.f, 0.f, 0.f, 0.f};
#pragma unroll
        for (int r = 0; r < 16; r += 4) {
            const float4 uu = *(const float4*)&u_lds[i0 + r];
            po[0] = fmaf(uu.x, cv[r + 0], po[0]);
            po[1] = fmaf(uu.y, cv[r + 1], po[1]);
            po[2] = fmaf(uu.z, cv[r + 2], po[2]);
            po[3] = fmaf(uu.w, cv[r + 3], po[3]);
        }
        float o = (po[0] + po[1]) + (po[2] + po[3]);
        o += __shfl_xor(o, 1);
        o += __shfl_xor(o, 2);

        if (r4 == 0)
            Oflat[((size_t)b_ * TT + t) * 1024 + h_ * 64 + c] = o - w;

        // publish staged t+1 values into the other buffer
        if (loader && (t + 1) < TT) {
            *(float4*)&vals[cur ^ 1][larr][loff] = pf[cur ^ 1];
        }
        __syncthreads();
    }
}

// ---------------------------------------------------------------------------
extern "C" void kernel_launch(void* const* d_in, const int* in_sizes, int n_in,
                              void* d_out, int out_size, void* d_ws, size_t ws_size,
                              hipStream_t stream)
{
    const float* x    = (const float*)d_in[0];
    const float* W_q  = (const float*)d_in[1];
    const float* W_k  = (const float*)d_in[2];
    const float* W_v  = (const float*)d_in[3];
    const float* Wg_K = (const float*)d_in[4];
    const float* bg_K = (const float*)d_in[5];
    const float* Wg_C = (const float*)d_in[6];
    const float* bg_C = (const float*)d_in[7];
    const float* W_o  = (const float*)d_in[8];

    float* ws = (float*)d_ws;
    const size_t S = (size_t)BB * NH * TT * 64;   // 8,388,608 floats per array
    float* Qp = ws + 0 * S;
    float* Kp = ws + 1 * S;
    float* Vp = ws + 2 * S;
    float* AK = ws + 3 * S;
    float* AC = ws + 4 * S;
    float* Of = ws + 5 * S;                        // [8192][1024]

    dim3 grid(BT / 128, 1024 / 128);
    dim3 blk(256);

    gemm_kernel<<<grid, blk, 0, stream>>>(x, W_q,  nullptr, Qp, 0);
    gemm_kernel<<<grid, blk, 0, stream>>>(x, W_k,  nullptr, Kp, 0);
    gemm_kernel<<<grid, blk, 0, stream>>>(x, W_v,  nullptr, Vp, 0);
    gemm_kernel<<<grid, blk, 0, stream>>>(x, Wg_K, bg_K,    AK, 1);
    gemm_kernel<<<grid, blk, 0, stream>>>(x, Wg_C, bg_C,    AC, 1);

    scan_kernel<<<dim3(BB * NH), blk, 0, stream>>>(Qp, Kp, Vp, AK, AC, Of);

    gemm_kernel<<<grid, blk, 0, stream>>>(Of, W_o, nullptr, (float*)d_out, 2);
}

// Round 3
// 3552.046 us; speedup vs baseline: 1.0628x; 1.0628x over previous
//
#include <hip/hip_runtime.h>
#include <hip/hip_bf16.h>

#define DMODEL 1024
#define NH     16
#define BB     4
#define TT     2048
#define BT     (BB * TT)   // 8192

// chunked-scan geometry
#define LDF    68
#define FB     4352        // 64*68 floats per full LDS buffer
#define LDH    36
#define HB     2304        // 64*36 floats per half buffer

// kernel-C LDS pool offsets (floats)
#define C_B0   0
#define C_B1   FB
#define C_B2   (2*FB)
#define C_B3   (3*FB)
#define C_B4   (4*FB)
#define C_B5   (5*FB)
#define C_HV   (4*FB)
#define C_HC   (4*FB + HB)
#define C_HG   (4*FB + 2*HB)
#define C_HK   (4*FB + 3*HB)
#define C_B6   (4*FB + 4*HB)
#define C_B7   (C_B6 + FB)
#define C_POOL (C_B7 + FB)   // 35328 floats = 141,312 B

// ===========================================================================
// fp32 tiled GEMM (unchanged from round 1)
// ===========================================================================
__global__ __launch_bounds__(256) void gemm_kernel(
    const float* __restrict__ A,
    const float* __restrict__ Bw,
    const float* __restrict__ bias,
    float* __restrict__ out,
    int mode)
{
    __shared__ __align__(16) float As[16][132];
    __shared__ __align__(16) float Bs[16][132];

    const int tid = threadIdx.x;
    const int tm = tid >> 4;
    const int tn = tid & 15;
    const int m0 = blockIdx.x * 128;
    const int n0 = blockIdx.y * 128;

    float acc[8][8];
#pragma unroll
    for (int i = 0; i < 8; ++i)
#pragma unroll
        for (int j = 0; j < 8; ++j) acc[i][j] = 0.f;

    const int arow = tid >> 2;
    const int akq  = (tid & 3) * 4;
    const int brow = tid >> 5;
    const int bnq  = (tid & 31) * 4;

    for (int k0 = 0; k0 < 1024; k0 += 16) {
#pragma unroll
        for (int it = 0; it < 2; ++it) {
            const int mr = it * 64 + arow;
            const float4 va = *(const float4*)(A + (size_t)(m0 + mr) * 1024 + k0 + akq);
            As[akq + 0][mr] = va.x;
            As[akq + 1][mr] = va.y;
            As[akq + 2][mr] = va.z;
            As[akq + 3][mr] = va.w;
        }
#pragma unroll
        for (int it = 0; it < 2; ++it) {
            const int kr = it * 8 + brow;
            const float4 vb = *(const float4*)(Bw + (size_t)(k0 + kr) * 1024 + n0 + bnq);
            *(float4*)&Bs[kr][bnq] = vb;
        }
        __syncthreads();
#pragma unroll
        for (int k = 0; k < 16; ++k) {
            float a[8], b[8];
            *(float4*)&a[0] = *(const float4*)&As[k][tm * 8];
            *(float4*)&a[4] = *(const float4*)&As[k][tm * 8 + 4];
            *(float4*)&b[0] = *(const float4*)&Bs[k][tn * 8];
            *(float4*)&b[4] = *(const float4*)&Bs[k][tn * 8 + 4];
#pragma unroll
            for (int i = 0; i < 8; ++i)
#pragma unroll
                for (int j = 0; j < 8; ++j)
                    acc[i][j] = fmaf(a[i], b[j], acc[i][j]);
        }
        __syncthreads();
    }

    if (mode == 2) {
#pragma unroll
        for (int i = 0; i < 8; ++i) {
            const int m = m0 + tm * 8 + i;
            float* dst = out + (size_t)m * 1024 + n0 + tn * 8;
            *(float4*)dst       = make_float4(acc[i][0], acc[i][1], acc[i][2], acc[i][3]);
            *((float4*)dst + 1) = make_float4(acc[i][4], acc[i][5], acc[i][6], acc[i][7]);
        }
    } else {
        const int nn = n0 + tn * 8;
        const int h = nn >> 6;
        const int d = nn & 63;
        float bb[8];
        if (mode == 1) {
#pragma unroll
            for (int j = 0; j < 8; ++j) bb[j] = bias[nn + j];
        }
#pragma unroll
        for (int i = 0; i < 8; ++i) {
            const int m  = m0 + tm * 8 + i;
            const int b_ = m >> 11;
            const int t_ = m & 2047;
            float v[8];
#pragma unroll
            for (int j = 0; j < 8; ++j) {
                float x = acc[i][j];
                if (mode == 1) x = 1.f / (1.f + expf(-(x + bb[j])));
                v[j] = x;
            }
            float* dst = out + ((size_t)((b_ * NH + h) * TT + t_) << 6) + d;
            *(float4*)dst       = make_float4(v[0], v[1], v[2], v[3]);
            *((float4*)dst + 1) = make_float4(v[4], v[5], v[6], v[7]);
        }
    }
}

// ===========================================================================
// shared helpers for the chunked path
// ===========================================================================
__device__ inline float4 f4mul(float4 a, float4 b) {
    return make_float4(a.x*b.x, a.y*b.y, a.z*b.z, a.w*b.w);
}
__device__ inline float4 f4div(float4 a, float4 b) {
    return make_float4(a.x/b.x, a.y/b.y, a.z/b.z, a.w/b.w);
}

// stage a 64x64 fp32 tile (global row stride 64) into LDS [64][LDF]
__device__ inline void stage64(float* sm, int off, const float* __restrict__ g, int tid)
{
    const int row = tid >> 2, c0 = (tid & 3) * 16;
#pragma unroll
    for (int q = 0; q < 4; ++q) {
        float4 v = *(const float4*)&g[(size_t)row * 64 + c0 + q * 4];
        *(float4*)&sm[off + row * LDF + c0 + q * 4] = v;
    }
}

// stage 64x32 half-tile (cols [vh*32, vh*32+32) of a stride-64 source) into [64][LDH]
__device__ inline void stage32(float* sm, int off, const float* __restrict__ g, int vh, int tid)
{
    const int row = tid >> 2, c0 = (tid & 3) * 8;
#pragma unroll
    for (int q = 0; q < 2; ++q) {
        float4 v = *(const float4*)&g[(size_t)row * 64 + vh * 32 + c0 + q * 4];
        *(float4*)&sm[off + row * LDH + c0 + q * 4] = v;
    }
}

// C[m][n] = sum_kk A[kk][m]*B[kk][n]  (both k-major, stride LDF). Write to global (stride 64).
// SWA: A buffer is XOR-swizzled (col4 ^= (row>>2)&7).
template<bool SWA>
__device__ inline void mmTN_g(const float* sm, int offA, int offB,
                              float* __restrict__ gout, int tid)
{
    const int tm = tid >> 4, tn = tid & 15;
    float acc[4][4] = {};
    for (int k0 = 0; k0 < 64; k0 += 4) {
        float4 a[4], b[4];
#pragma unroll
        for (int q = 0; q < 4; ++q) {
            const int row = k0 + q;
            const int ca = SWA ? (tm ^ ((row >> 2) & 7)) : tm;
            a[q] = *(const float4*)&sm[offA + row * LDF + ca * 4];
            b[q] = *(const float4*)&sm[offB + row * LDF + tn * 4];
        }
#pragma unroll
        for (int q = 0; q < 4; ++q) {
            const float* ap = (const float*)&a[q];
            const float* bp = (const float*)&b[q];
#pragma unroll
            for (int i = 0; i < 4; ++i)
#pragma unroll
                for (int j = 0; j < 4; ++j)
                    acc[i][j] = fmaf(ap[i], bp[j], acc[i][j]);
        }
    }
#pragma unroll
    for (int i = 0; i < 4; ++i)
        *(float4*)&gout[(size_t)(tm*4 + i) * 64 + tn * 4] =
            make_float4(acc[i][0], acc[i][1], acc[i][2], acc[i][3]);
}

// C[m][n] = sum_kk A[m][kk]*B[n][kk]; A row-major unswizzled, B row-major SWIZZLED.
// mask: 0 none, 1 keep n<=m, 2 keep n<m. Write LDS [m][n] stride LDF.
__device__ inline void mmNT_lds(float* sm, int offA, int offB, int offC,
                                int mask, int tid)
{
    const int tm = tid >> 4, tn = tid & 15;
    float acc[4][4] = {};
    for (int k0 = 0; k0 < 64; k0 += 4) {
        float4 a[4], b[4];
#pragma unroll
        for (int i = 0; i < 4; ++i)
            a[i] = *(const float4*)&sm[offA + (tm*4 + i) * LDF + k0];
        const int cc = ((k0 >> 2) ^ (tn & 7)) * 4;
#pragma unroll
        for (int j = 0; j < 4; ++j)
            b[j] = *(const float4*)&sm[offB + (tn*4 + j) * LDF + cc];
#pragma unroll
        for (int i = 0; i < 4; ++i) {
            const float* ap = (const float*)&a[i];
#pragma unroll
            for (int j = 0; j < 4; ++j) {
                const float* bp = (const float*)&b[j];
                acc[i][j] = fmaf(ap[0], bp[0], acc[i][j]);
                acc[i][j] = fmaf(ap[1], bp[1], acc[i][j]);
                acc[i][j] = fmaf(ap[2], bp[2], acc[i][j]);
                acc[i][j] = fmaf(ap[3], bp[3], acc[i][j]);
            }
        }
    }
#pragma unroll
    for (int i = 0; i < 4; ++i) {
        const int m = tm*4 + i;
#pragma unroll
        for (int j = 0; j < 4; ++j) {
            const int n = tn*4 + j;
            float v = acc[i][j];
            if (mask == 1 && n > m)  v = 0.f;
            if (mask == 2 && n >= m) v = 0.f;
            sm[offC + m * LDF + n] = v;
        }
    }
}

// acc[i][j] (+/-)= sum_kk A[m][kk]*B[kk][n]; A row-major stride LDF; B k-major stride LDF.
// SWB: B buffer swizzled.
template<bool SWB, bool NEG>
__device__ inline void mmNN_acc(const float* sm, int offA, int offB,
                                float (&acc)[4][4], int tid)
{
    const int tm = tid >> 4, tn = tid & 15;
    for (int k0 = 0; k0 < 64; k0 += 4) {
        float4 a[4], b[4];
#pragma unroll
        for (int i = 0; i < 4; ++i)
            a[i] = *(const float4*)&sm[offA + (tm*4 + i) * LDF + k0];
        const int ctn = SWB ? ((tn ^ ((k0 >> 2) & 7)) * 4) : (tn * 4);
#pragma unroll
        for (int q = 0; q < 4; ++q)
            b[q] = *(const float4*)&sm[offB + (k0 + q) * LDF + ctn];
#pragma unroll
        for (int i = 0; i < 4; ++i) {
            const float* ap = (const float*)&a[i];
#pragma unroll
            for (int q = 0; q < 4; ++q) {
                const float av = NEG ? -ap[q] : ap[q];
                const float* bp = (const float*)&b[q];
#pragma unroll
                for (int j = 0; j < 4; ++j)
                    acc[i][j] = fmaf(av, bp[j], acc[i][j]);
            }
        }
    }
}

// plain NN into LDS (no swizzle, no mask)
__device__ inline void mmNN_lds(float* sm, int offA, int offB, int offC, int tid)
{
    float acc[4][4] = {};
    mmNN_acc<false, false>(sm, offA, offB, acc, tid);
    const int tm = tid >> 4, tn = tid & 15;
#pragma unroll
    for (int i = 0; i < 4; ++i)
        *(float4*)&sm[offC + (tm*4 + i) * LDF + tn * 4] =
            make_float4(acc[i][0], acc[i][1], acc[i][2], acc[i][3]);
}

// acc[i][j] (+/-)= sum_kk A[m][kk]*B[kk][n], B half-width stride LDH (32 cols, 2/thread)
template<bool NEG>
__device__ inline void mmNN32_acc(const float* sm, int offA, int offB,
                                  float (&acc)[4][2], int tid)
{
    const int tm = tid >> 4, tn = tid & 15;
    for (int k0 = 0; k0 < 64; k0 += 4) {
        float4 a[4];
        float2 b[4];
#pragma unroll
        for (int i = 0; i < 4; ++i)
            a[i] = *(const float4*)&sm[offA + (tm*4 + i) * LDF + k0];
#pragma unroll
        for (int q = 0; q < 4; ++q)
            b[q] = *(const float2*)&sm[offB + (k0 + q) * LDH + tn * 2];
#pragma unroll
        for (int i = 0; i < 4; ++i) {
            const float* ap = (const float*)&a[i];
#pragma unroll
            for (int q = 0; q < 4; ++q) {
                const float av = NEG ? -ap[q] : ap[q];
                acc[i][0] = fmaf(av, b[q].x, acc[i][0]);
                acc[i][1] = fmaf(av, b[q].y, acc[i][1]);
            }
        }
    }
}

// ===========================================================================
// Kernel A: per-(chain,chunk) summaries.  grid = 64*32, block = 256
// outputs: A_S = KtKt, A_C = QtV, M = Kt*KhC, A_Gv = Kt*(beta V), DK, DC
// ===========================================================================
__global__ __launch_bounds__(256) void chunk_sum_kernel(
    const float* __restrict__ Qp, const float* __restrict__ Kp,
    const float* __restrict__ Vp, const float* __restrict__ AKp,
    const float* __restrict__ ACp,
    float* __restrict__ ASg, float* __restrict__ ACg,
    float* __restrict__ Mg,  float* __restrict__ AGvg,
    float* __restrict__ DKg, float* __restrict__ DCg)
{
    __shared__ float sm[6 * FB];
    const int bid = blockIdx.x, tid = threadIdx.x;
    const int ch = bid >> 5, ck = bid & 31;
    const size_t ib = ((size_t)ch * TT + ck * 64) * 64;

    stage64(sm, 0,      Qp  + ib, tid);
    stage64(sm, FB,     Kp  + ib, tid);
    stage64(sm, 2*FB,   AKp + ib, tid);
    stage64(sm, 3*FB,   ACp + ib, tid);
    stage64(sm, 4*FB,   Vp  + ib, tid);
    __syncthreads();

    // cumulative products in place (PK over aK, PC over aC)
    if (tid < 128) {
        const int i = tid & 63;
        const int off = (tid < 64) ? 2*FB : 3*FB;
        float p = 1.f;
        for (int t = 0; t < 64; ++t) {
            p *= sm[off + t * LDF + i];
            sm[off + t * LDF + i] = p;
        }
        if (tid < 64) DKg[(size_t)bid * 64 + i] = p;
        else          DCg[(size_t)bid * 64 + i] = p;
    }
    __syncthreads();

    // transform: KhC -> B0 (over q), Kt -> B1 (over k), Qt(swizzled) -> B5
    {
        const int row = tid >> 2, cb = (tid & 3) * 16;
        const int sx = (row >> 2) & 7;
#pragma unroll
        for (int w = 0; w < 4; ++w) {
            const int c = cb + w * 4;
            float4 q  = *(const float4*)&sm[0    + row * LDF + c];
            float4 k  = *(const float4*)&sm[FB   + row * LDF + c];
            float4 pk = *(const float4*)&sm[2*FB + row * LDF + c];
            float4 pc = *(const float4*)&sm[3*FB + row * LDF + c];
            *(float4*)&sm[0  + row * LDF + c] = f4mul(k, pc);   // KhC
            *(float4*)&sm[FB + row * LDF + c] = f4div(k, pk);   // Kt
            const int csw = (((c >> 2) ^ sx) << 2);
            *(float4*)&sm[5*FB + row * LDF + csw] = f4div(q, pc); // Qt (sw)
        }
    }
    __syncthreads();

    mmTN_g<false>(sm, FB,   FB,   ASg  + (size_t)bid * 4096, tid); // A_S
    mmTN_g<true >(sm, 5*FB, 4*FB, ACg  + (size_t)bid * 4096, tid); // A_C
    mmTN_g<false>(sm, FB,   0,    Mg   + (size_t)bid * 4096, tid); // M
    mmNT_lds(sm, 0, 5*FB, 2*FB, 2, tid);                           // beta (strict) -> B2
    __syncthreads();
    mmNN_lds(sm, 2*FB, 4*FB, 3*FB, tid);                           // T1 = beta*V -> B3
    __syncthreads();
    mmTN_g<false>(sm, FB, 3*FB, AGvg + (size_t)bid * 4096, tid);   // A_Gv
}

// ===========================================================================
// Kernel B: sequential chunk-state composition. grid = 64, block = 256
// S' = DK(S+A_S)DK ; C' = DC(C+A_C) ; G' = DK(G + M*C + A_Gv)
// writes the BEFORE-chunk states per chunk.
// ===========================================================================
__global__ __launch_bounds__(256) void state_scan_kernel(
    const float* __restrict__ ASg, const float* __restrict__ ACg,
    const float* __restrict__ Mg,  const float* __restrict__ AGvg,
    const float* __restrict__ DKg, const float* __restrict__ DCg,
    float* __restrict__ S0g, float* __restrict__ C0g, float* __restrict__ G0g)
{
    __shared__ float sm[5 * FB];
    __shared__ float dkv[64], dcv[64];
    const int ch = blockIdx.x, tid = threadIdx.x;

    for (int e = tid; e < 3 * FB; e += 256) sm[e] = 0.f;
    __syncthreads();

    const int row = tid >> 2, c0 = (tid & 3) * 16;

    for (int ck = 0; ck < 32; ++ck) {
        const size_t sb = (size_t)(ch * 32 + ck) * 4096;
        // write out BEFORE-chunk states
#pragma unroll
        for (int q = 0; q < 4; ++q) {
            const int c = c0 + q * 4;
            *(float4*)&S0g[sb + row * 64 + c] = *(const float4*)&sm[0    + row * LDF + c];
            *(float4*)&C0g[sb + row * 64 + c] = *(const float4*)&sm[FB   + row * LDF + c];
            *(float4*)&G0g[sb + row * 64 + c] = *(const float4*)&sm[2*FB + row * LDF + c];
        }
        stage64(sm, 3 * FB, Mg + sb, tid);
        if (tid < 64)       dkv[tid]      = DKg[sb / 64 + tid];
        else if (tid < 128) dcv[tid - 64] = DCg[sb / 64 + tid - 64];
        __syncthreads();
        mmNN_lds(sm, 3 * FB, FB, 4 * FB, tid);   // MC = M * C
        __syncthreads();

        const float dki = dkv[row], dci = dcv[row];
#pragma unroll
        for (int w = 0; w < 4; ++w) {
            const int c = c0 + w * 4;
            const size_t e = sb + row * 64 + c;
            float4 dkj = *(const float4*)&dkv[c];
            float4 s   = *(float4*)&sm[0 + row * LDF + c];
            float4 as  = *(const float4*)&ASg[e];
            s.x = dki * dkj.x * (s.x + as.x);
            s.y = dki * dkj.y * (s.y + as.y);
            s.z = dki * dkj.z * (s.z + as.z);
            s.w = dki * dkj.w * (s.w + as.w);
            *(float4*)&sm[0 + row * LDF + c] = s;

            float4 cc = *(float4*)&sm[FB + row * LDF + c];
            float4 ac = *(const float4*)&ACg[e];
            cc.x = dci * (cc.x + ac.x);
            cc.y = dci * (cc.y + ac.y);
            cc.z = dci * (cc.z + ac.z);
            cc.w = dci * (cc.w + ac.w);
            *(float4*)&sm[FB + row * LDF + c] = cc;

            float4 g  = *(float4*)&sm[2*FB + row * LDF + c];
            float4 ag = *(const float4*)&AGvg[e];
            float4 mc = *(const float4*)&sm[4*FB + row * LDF + c];
            g.x = dki * (g.x + mc.x + ag.x);
            g.y = dki * (g.y + mc.y + ag.y);
            g.z = dki * (g.z + mc.z + ag.z);
            g.w = dki * (g.w + mc.w + ag.w);
            *(float4*)&sm[2*FB + row * LDF + c] = g;
        }
        __syncthreads();
    }
}

// ===========================================================================
// Kernel C: per-(chain,chunk) outputs. grid = 64*32, block = 256
// O = uh*C0 + (delta.incl)V - Qh*G0 - gamma*KC,  KC = KhC*C0 + (beta.strict)V
// uh = (Qh*S0 + gamma*Kt) .* PK .* PC
// ===========================================================================
__global__ __launch_bounds__(256) void chunk_out_kernel(
    const float* __restrict__ Qp, const float* __restrict__ Kp,
    const float* __restrict__ Vp, const float* __restrict__ AKp,
    const float* __restrict__ ACp,
    const float* __restrict__ S0g, const float* __restrict__ C0g,
    const float* __restrict__ G0g, float* __restrict__ Of)
{
    __shared__ float sm[C_POOL];
    const int bid = blockIdx.x, tid = threadIdx.x;
    const int ch = bid >> 5, ck = bid & 31;
    const size_t ib = ((size_t)ch * TT + ck * 64) * 64;

    stage64(sm, C_B0, Qp  + ib, tid);
    stage64(sm, C_B1, Kp  + ib, tid);
    stage64(sm, C_B2, AKp + ib, tid);
    stage64(sm, C_B3, ACp + ib, tid);
    __syncthreads();

    if (tid < 128) {
        const int i = tid & 63;
        const int off = (tid < 64) ? C_B2 : C_B3;
        float p = 1.f;
        for (int t = 0; t < 64; ++t) {
            p *= sm[off + t * LDF + i];
            sm[off + t * LDF + i] = p;
        }
    }
    __syncthreads();

    // transform: Qh->B0, KhC->B1, PP->B2, Qt(sw)->B4, Kt(sw)->B5
    {
        const int row = tid >> 2, cb = (tid & 3) * 16;
        const int sx = (row >> 2) & 7;
#pragma unroll
        for (int w = 0; w < 4; ++w) {
            const int c = cb + w * 4;
            float4 q  = *(const float4*)&sm[C_B0 + row * LDF + c];
            float4 k  = *(const float4*)&sm[C_B1 + row * LDF + c];
            float4 pk = *(const float4*)&sm[C_B2 + row * LDF + c];
            float4 pc = *(const float4*)&sm[C_B3 + row * LDF + c];
            *(float4*)&sm[C_B0 + row * LDF + c] = f4mul(q, pk);   // Qh
            *(float4*)&sm[C_B1 + row * LDF + c] = f4mul(k, pc);   // KhC
            *(float4*)&sm[C_B2 + row * LDF + c] = f4mul(pk, pc);  // PP
            const int csw = (((c >> 2) ^ sx) << 2);
            *(float4*)&sm[C_B4 + row * LDF + csw] = f4div(q, pc); // Qt (sw)
            *(float4*)&sm[C_B5 + row * LDF + csw] = f4div(k, pk); // Kt (sw)
        }
    }
    __syncthreads();

    stage64(sm, C_B6, S0g + (size_t)bid * 4096, tid);
    mmNT_lds(sm, C_B0, C_B5, C_B3, 1, tid);        // gamma (incl) -> B3
    __syncthreads();

    {   // uh = (Qh*S0 + gamma*Kt) .* PP  -> B7
        float acc[4][4] = {};
        mmNN_acc<false, false>(sm, C_B0, C_B6, acc, tid);
        mmNN_acc<true,  false>(sm, C_B3, C_B5, acc, tid);
        const int tm = tid >> 4, tn = tid & 15;
#pragma unroll
        for (int i = 0; i < 4; ++i) {
            const int m = tm * 4 + i;
            const float4 pp = *(const float4*)&sm[C_B2 + m * LDF + tn * 4];
            *(float4*)&sm[C_B7 + m * LDF + tn * 4] =
                make_float4(acc[i][0] * pp.x, acc[i][1] * pp.y,
                            acc[i][2] * pp.z, acc[i][3] * pp.w);
        }
    }
    __syncthreads();

    mmNT_lds(sm, C_B1, C_B4, C_B2, 2, tid);        // beta (strict) -> B2
    mmNT_lds(sm, C_B7, C_B4, C_B6, 1, tid);        // delta (incl)  -> B6
    __syncthreads();

    const int b_ = ch >> 4, h_ = ch & 15;
    const int tm = tid >> 4, tn = tid & 15;

    for (int vh = 0; vh < 2; ++vh) {
        stage32(sm, C_HV, Vp + ib,                    vh, tid);
        stage32(sm, C_HC, C0g + (size_t)bid * 4096,   vh, tid);
        stage32(sm, C_HG, G0g + (size_t)bid * 4096,   vh, tid);
        __syncthreads();
        {   // KC half = KhC*C0h + beta*Vh -> HK
            float acc[4][2] = {};
            mmNN32_acc<false>(sm, C_B1, C_HC, acc, tid);
            mmNN32_acc<false>(sm, C_B2, C_HV, acc, tid);
#pragma unroll
            for (int i = 0; i < 4; ++i) {
                sm[C_HK + (tm*4 + i) * LDH + tn*2 + 0] = acc[i][0];
                sm[C_HK + (tm*4 + i) * LDH + tn*2 + 1] = acc[i][1];
            }
        }
        __syncthreads();
        {   // O half = uh*C0h + delta*Vh - Qh*G0h - gamma*KCh
            float acc[4][2] = {};
            mmNN32_acc<false>(sm, C_B7, C_HC, acc, tid);
            mmNN32_acc<false>(sm, C_B6, C_HV, acc, tid);
            mmNN32_acc<true >(sm, C_B0, C_HG, acc, tid);
            mmNN32_acc<true >(sm, C_B3, C_HK, acc, tid);
#pragma unroll
            for (int i = 0; i < 4; ++i) {
                const int t = ck * 64 + tm * 4 + i;
                const size_t o = ((size_t)b_ * TT + t) * 1024 + h_ * 64 + vh * 32 + tn * 2;
                *(float2*)&Of[o] = make_float2(acc[i][0], acc[i][1]);
            }
        }
        __syncthreads();
    }
}

// ===========================================================================
// Fallback: round-1 sequential scan (used only if ws_size is too small)
// ===========================================================================
__global__ __launch_bounds__(256) void scan_kernel(
    const float* __restrict__ Q,  const float* __restrict__ Kv,
    const float* __restrict__ V,  const float* __restrict__ AK,
    const float* __restrict__ AC, float* __restrict__ Oflat)
{
    const int bh  = blockIdx.x;
    const int b_  = bh >> 4;
    const int h_  = bh & 15;
    const int tid = threadIdx.x;
    const int c   = tid >> 2;
    const int r4  = tid & 3;
    const int i0  = r4 * 16;

    __shared__ __align__(16) float vals[2][5][64];
    __shared__ __align__(16) float u_lds[64];

    const size_t base = (size_t)bh * TT * 64;
    const float* arrs[5] = {Q + base, Kv + base, V + base, AK + base, AC + base};

    float sk[16], cv[16], g[16];
#pragma unroll
    for (int r = 0; r < 16; ++r) { sk[r] = 0.f; cv[r] = 0.f; g[r] = 0.f; }

    const bool loader = (tid < 80);
    const int  larr = tid >> 4;
    const int  loff = (tid & 15) * 4;
    float4 pf[2];

    if (loader) {
        pf[0] = *(const float4*)(arrs[larr] + 0 * 64 + loff);
        pf[1] = *(const float4*)(arrs[larr] + 1 * 64 + loff);
        *(float4*)&vals[0][larr][loff] = pf[0];
    }
    __syncthreads();

    for (int t = 0; t < TT; ++t) {
        const int cur = t & 1;
        if (loader && (t + 2) < TT)
            pf[cur] = *(const float4*)(arrs[larr] + (size_t)(t + 2) * 64 + loff);

        float qv[16], kv[16], ak[16], ac[16];
#pragma unroll
        for (int r = 0; r < 16; r += 4) {
            *(float4*)&qv[r] = *(const float4*)&vals[cur][0][i0 + r];
            *(float4*)&kv[r] = *(const float4*)&vals[cur][1][i0 + r];
            *(float4*)&ak[r] = *(const float4*)&vals[cur][3][i0 + r];
            *(float4*)&ac[r] = *(const float4*)&vals[cur][4][i0 + r];
        }
        const float vc  = vals[cur][2][c];
        const float kc  = vals[cur][1][c];
        const float akc = vals[cur][3][c];

        float pk[4] = {0.f, 0.f, 0.f, 0.f};
#pragma unroll
        for (int r = 0; r < 16; ++r) {
            const float s = ac[r] * cv[r];
            pk[r & 3] = fmaf(kv[r], s, pk[r & 3]);
            cv[r] = fmaf(qv[r], vc, s);
        }
        float ktc = (pk[0] + pk[1]) + (pk[2] + pk[3]);
        ktc += __shfl_xor(ktc, 1);
        ktc += __shfl_xor(ktc, 2);

        float pu[4] = {0.f, 0.f, 0.f, 0.f};
        float pw[4] = {0.f, 0.f, 0.f, 0.f};
#pragma unroll
        for (int r = 0; r < 16; ++r) {
            g[r]  = fmaf(ak[r], g[r], kv[r] * ktc);
            sk[r] = fmaf(ak[r] * akc, sk[r], kv[r] * kc);
            pu[r & 3] = fmaf(qv[r], sk[r], pu[r & 3]);
            pw[r & 3] = fmaf(qv[r], g[r],  pw[r & 3]);
        }
        float u = (pu[0] + pu[1]) + (pu[2] + pu[3]);
        u += __shfl_xor(u, 1);
        u += __shfl_xor(u, 2);
        float w = (pw[0] + pw[1]) + (pw[2] + pw[3]);
        w += __shfl_xor(w, 1);
        w += __shfl_xor(w, 2);

        if (r4 == 0) u_lds[c] = u;
        __syncthreads();

        float po[4] = {0.f, 0.f, 0.f, 0.f};
#pragma unroll
        for (int r = 0; r < 16; r += 4) {
            const float4 uu = *(const float4*)&u_lds[i0 + r];
            po[0] = fmaf(uu.x, cv[r + 0], po[0]);
            po[1] = fmaf(uu.y, cv[r + 1], po[1]);
            po[2] = fmaf(uu.z, cv[r + 2], po[2]);
            po[3] = fmaf(uu.w, cv[r + 3], po[3]);
        }
        float o = (po[0] + po[1]) + (po[2] + po[3]);
        o += __shfl_xor(o, 1);
        o += __shfl_xor(o, 2);

        if (r4 == 0)
            Oflat[((size_t)b_ * TT + t) * 1024 + h_ * 64 + c] = o - w;

        if (loader && (t + 1) < TT)
            *(float4*)&vals[cur ^ 1][larr][loff] = pf[cur ^ 1];
        __syncthreads();
    }
}

// ===========================================================================
extern "C" void kernel_launch(void* const* d_in, const int* in_sizes, int n_in,
                              void* d_out, int out_size, void* d_ws, size_t ws_size,
                              hipStream_t stream)
{
    const float* x    = (const float*)d_in[0];
    const float* W_q  = (const float*)d_in[1];
    const float* W_k  = (const float*)d_in[2];
    const float* W_v  = (const float*)d_in[3];
    const float* Wg_K = (const float*)d_in[4];
    const float* bg_K = (const float*)d_in[5];
    const float* Wg_C = (const float*)d_in[6];
    const float* bg_C = (const float*)d_in[7];
    const float* W_o  = (const float*)d_in[8];

    float* ws = (float*)d_ws;
    const size_t S1 = (size_t)BB * NH * TT * 64;   // 8,388,608 floats
    float* Qp = ws + 0 * S1;
    float* Kp = ws + 1 * S1;
    float* Vp = ws + 2 * S1;
    float* AK = ws + 3 * S1;
    float* AC = ws + 4 * S1;
    float* Of = ws + 5 * S1;

    dim3 grid(BT / 128, 1024 / 128);
    dim3 blk(256);

    gemm_kernel<<<grid, blk, 0, stream>>>(x, W_q,  nullptr, Qp, 0);
    gemm_kernel<<<grid, blk, 0, stream>>>(x, W_k,  nullptr, Kp, 0);
    gemm_kernel<<<grid, blk, 0, stream>>>(x, W_v,  nullptr, Vp, 0);
    gemm_kernel<<<grid, blk, 0, stream>>>(x, Wg_K, bg_K,    AK, 1);
    gemm_kernel<<<grid, blk, 0, stream>>>(x, Wg_C, bg_C,    AC, 1);

    const size_t need = (13 * S1 + 2 * (size_t)64 * 32 * 64) * 4;
    if (ws_size >= need) {
        float* ASg  = ws + 6  * S1;
        float* ACg  = ws + 7  * S1;
        float* Mg   = ws + 8  * S1;
        float* AGvg = ws + 9  * S1;
        float* S0g  = ws + 10 * S1;
        float* C0g  = ws + 11 * S1;
        float* G0g  = ws + 12 * S1;
        float* DKg  = ws + 13 * S1;
        float* DCg  = DKg + (size_t)64 * 32 * 64;

        chunk_sum_kernel<<<dim3(2048), blk, 0, stream>>>(
            Qp, Kp, Vp, AK, AC, ASg, ACg, Mg, AGvg, DKg, DCg);
        state_scan_kernel<<<dim3(64), blk, 0, stream>>>(
            ASg, ACg, Mg, AGvg, DKg, DCg, S0g, C0g, G0g);
        chunk_out_kernel<<<dim3(2048), blk, 0, stream>>>(
            Qp, Kp, Vp, AK, AC, S0g, C0g, G0g, Of);
    } else {
        scan_kernel<<<dim3(64), blk, 0, stream>>>(Qp, Kp, Vp, AK, AC, Of);
    }

    gemm_kernel<<<grid, blk, 0, stream>>>(Of, W_o, nullptr, (float*)d_out, 2);
}

// Round 4
// 2474.789 us; speedup vs baseline: 1.5254x; 1.4353x over previous
//
#include <hip/hip_runtime.h>
#include <hip/hip_bf16.h>

#define DMODEL 1024
#define NH     16
#define BB     4
#define TT     2048
#define BT     (BB * TT)   // 8192

// chunked-scan geometry
#define LDF    68
#define FB     4352        // 64*68 floats per full LDS buffer
#define LDH    36
#define HB     2304        // 64*36 floats per half buffer

// kernel-C LDS pool offsets (floats)
#define C_B0   0
#define C_B1   FB
#define C_B2   (2*FB)
#define C_B3   (3*FB)
#define C_B4   (4*FB)
#define C_B5   (5*FB)
#define C_HV   (4*FB)
#define C_HC   (4*FB + HB)
#define C_HG   (4*FB + 2*HB)
#define C_HK   (4*FB + 3*HB)
#define C_B6   (4*FB + 4*HB)
#define C_B7   (C_B6 + FB)
#define C_POOL (C_B7 + FB)   // 35328 floats = 141,312 B

// ===========================================================================
// fp32 tiled GEMM (unchanged)
// ===========================================================================
__global__ __launch_bounds__(256) void gemm_kernel(
    const float* __restrict__ A,
    const float* __restrict__ Bw,
    const float* __restrict__ bias,
    float* __restrict__ out,
    int mode)
{
    __shared__ __align__(16) float As[16][132];
    __shared__ __align__(16) float Bs[16][132];

    const int tid = threadIdx.x;
    const int tm = tid >> 4;
    const int tn = tid & 15;
    const int m0 = blockIdx.x * 128;
    const int n0 = blockIdx.y * 128;

    float acc[8][8];
#pragma unroll
    for (int i = 0; i < 8; ++i)
#pragma unroll
        for (int j = 0; j < 8; ++j) acc[i][j] = 0.f;

    const int arow = tid >> 2;
    const int akq  = (tid & 3) * 4;
    const int brow = tid >> 5;
    const int bnq  = (tid & 31) * 4;

    for (int k0 = 0; k0 < 1024; k0 += 16) {
#pragma unroll
        for (int it = 0; it < 2; ++it) {
            const int mr = it * 64 + arow;
            const float4 va = *(const float4*)(A + (size_t)(m0 + mr) * 1024 + k0 + akq);
            As[akq + 0][mr] = va.x;
            As[akq + 1][mr] = va.y;
            As[akq + 2][mr] = va.z;
            As[akq + 3][mr] = va.w;
        }
#pragma unroll
        for (int it = 0; it < 2; ++it) {
            const int kr = it * 8 + brow;
            const float4 vb = *(const float4*)(Bw + (size_t)(k0 + kr) * 1024 + n0 + bnq);
            *(float4*)&Bs[kr][bnq] = vb;
        }
        __syncthreads();
#pragma unroll
        for (int k = 0; k < 16; ++k) {
            float a[8], b[8];
            *(float4*)&a[0] = *(const float4*)&As[k][tm * 8];
            *(float4*)&a[4] = *(const float4*)&As[k][tm * 8 + 4];
            *(float4*)&b[0] = *(const float4*)&Bs[k][tn * 8];
            *(float4*)&b[4] = *(const float4*)&Bs[k][tn * 8 + 4];
#pragma unroll
            for (int i = 0; i < 8; ++i)
#pragma unroll
                for (int j = 0; j < 8; ++j)
                    acc[i][j] = fmaf(a[i], b[j], acc[i][j]);
        }
        __syncthreads();
    }

    if (mode == 2) {
#pragma unroll
        for (int i = 0; i < 8; ++i) {
            const int m = m0 + tm * 8 + i;
            float* dst = out + (size_t)m * 1024 + n0 + tn * 8;
            *(float4*)dst       = make_float4(acc[i][0], acc[i][1], acc[i][2], acc[i][3]);
            *((float4*)dst + 1) = make_float4(acc[i][4], acc[i][5], acc[i][6], acc[i][7]);
        }
    } else {
        const int nn = n0 + tn * 8;
        const int h = nn >> 6;
        const int d = nn & 63;
        float bb[8];
        if (mode == 1) {
#pragma unroll
            for (int j = 0; j < 8; ++j) bb[j] = bias[nn + j];
        }
#pragma unroll
        for (int i = 0; i < 8; ++i) {
            const int m  = m0 + tm * 8 + i;
            const int b_ = m >> 11;
            const int t_ = m & 2047;
            float v[8];
#pragma unroll
            for (int j = 0; j < 8; ++j) {
                float x = acc[i][j];
                if (mode == 1) x = 1.f / (1.f + expf(-(x + bb[j])));
                v[j] = x;
            }
            float* dst = out + ((size_t)((b_ * NH + h) * TT + t_) << 6) + d;
            *(float4*)dst       = make_float4(v[0], v[1], v[2], v[3]);
            *((float4*)dst + 1) = make_float4(v[4], v[5], v[6], v[7]);
        }
    }
}

// ===========================================================================
// shared helpers for the chunked path
// ===========================================================================
__device__ inline float4 f4mul(float4 a, float4 b) {
    return make_float4(a.x*b.x, a.y*b.y, a.z*b.z, a.w*b.w);
}
__device__ inline float4 f4div(float4 a, float4 b) {
    return make_float4(a.x/b.x, a.y/b.y, a.z/b.z, a.w/b.w);
}

__device__ inline void stage64(float* sm, int off, const float* __restrict__ g, int tid)
{
    const int row = tid >> 2, c0 = (tid & 3) * 16;
#pragma unroll
    for (int q = 0; q < 4; ++q) {
        float4 v = *(const float4*)&g[(size_t)row * 64 + c0 + q * 4];
        *(float4*)&sm[off + row * LDF + c0 + q * 4] = v;
    }
}

__device__ inline void stage32(float* sm, int off, const float* __restrict__ g, int vh, int tid)
{
    const int row = tid >> 2, c0 = (tid & 3) * 8;
#pragma unroll
    for (int q = 0; q < 2; ++q) {
        float4 v = *(const float4*)&g[(size_t)row * 64 + vh * 32 + c0 + q * 4];
        *(float4*)&sm[off + row * LDH + c0 + q * 4] = v;
    }
}

template<bool SWA>
__device__ inline void mmTN_g(const float* sm, int offA, int offB,
                              float* __restrict__ gout, int tid)
{
    const int tm = tid >> 4, tn = tid & 15;
    float acc[4][4] = {};
    for (int k0 = 0; k0 < 64; k0 += 4) {
        float4 a[4], b[4];
#pragma unroll
        for (int q = 0; q < 4; ++q) {
            const int row = k0 + q;
            const int ca = SWA ? (tm ^ ((row >> 2) & 7)) : tm;
            a[q] = *(const float4*)&sm[offA + row * LDF + ca * 4];
            b[q] = *(const float4*)&sm[offB + row * LDF + tn * 4];
        }
#pragma unroll
        for (int q = 0; q < 4; ++q) {
            const float* ap = (const float*)&a[q];
            const float* bp = (const float*)&b[q];
#pragma unroll
            for (int i = 0; i < 4; ++i)
#pragma unroll
                for (int j = 0; j < 4; ++j)
                    acc[i][j] = fmaf(ap[i], bp[j], acc[i][j]);
        }
    }
#pragma unroll
    for (int i = 0; i < 4; ++i)
        *(float4*)&gout[(size_t)(tm*4 + i) * 64 + tn * 4] =
            make_float4(acc[i][0], acc[i][1], acc[i][2], acc[i][3]);
}

__device__ inline void mmNT_lds(float* sm, int offA, int offB, int offC,
                                int mask, int tid)
{
    const int tm = tid >> 4, tn = tid & 15;
    float acc[4][4] = {};
    for (int k0 = 0; k0 < 64; k0 += 4) {
        float4 a[4], b[4];
#pragma unroll
        for (int i = 0; i < 4; ++i)
            a[i] = *(const float4*)&sm[offA + (tm*4 + i) * LDF + k0];
        const int cc = ((k0 >> 2) ^ (tn & 7)) * 4;
#pragma unroll
        for (int j = 0; j < 4; ++j)
            b[j] = *(const float4*)&sm[offB + (tn*4 + j) * LDF + cc];
#pragma unroll
        for (int i = 0; i < 4; ++i) {
            const float* ap = (const float*)&a[i];
#pragma unroll
            for (int j = 0; j < 4; ++j) {
                const float* bp = (const float*)&b[j];
                acc[i][j] = fmaf(ap[0], bp[0], acc[i][j]);
                acc[i][j] = fmaf(ap[1], bp[1], acc[i][j]);
                acc[i][j] = fmaf(ap[2], bp[2], acc[i][j]);
                acc[i][j] = fmaf(ap[3], bp[3], acc[i][j]);
            }
        }
    }
#pragma unroll
    for (int i = 0; i < 4; ++i) {
        const int m = tm*4 + i;
#pragma unroll
        for (int j = 0; j < 4; ++j) {
            const int n = tn*4 + j;
            float v = acc[i][j];
            if (mask == 1 && n > m)  v = 0.f;
            if (mask == 2 && n >= m) v = 0.f;
            sm[offC + m * LDF + n] = v;
        }
    }
}

template<bool SWB, bool NEG>
__device__ inline void mmNN_acc(const float* sm, int offA, int offB,
                                float (&acc)[4][4], int tid)
{
    const int tm = tid >> 4, tn = tid & 15;
    for (int k0 = 0; k0 < 64; k0 += 4) {
        float4 a[4], b[4];
#pragma unroll
        for (int i = 0; i < 4; ++i)
            a[i] = *(const float4*)&sm[offA + (tm*4 + i) * LDF + k0];
        const int ctn = SWB ? ((tn ^ ((k0 >> 2) & 7)) * 4) : (tn * 4);
#pragma unroll
        for (int q = 0; q < 4; ++q)
            b[q] = *(const float4*)&sm[offB + (k0 + q) * LDF + ctn];
#pragma unroll
        for (int i = 0; i < 4; ++i) {
            const float* ap = (const float*)&a[i];
#pragma unroll
            for (int q = 0; q < 4; ++q) {
                const float av = NEG ? -ap[q] : ap[q];
                const float* bp = (const float*)&b[q];
#pragma unroll
                for (int j = 0; j < 4; ++j)
                    acc[i][j] = fmaf(av, bp[j], acc[i][j]);
            }
        }
    }
}

__device__ inline void mmNN_lds(float* sm, int offA, int offB, int offC, int tid)
{
    float acc[4][4] = {};
    mmNN_acc<false, false>(sm, offA, offB, acc, tid);
    const int tm = tid >> 4, tn = tid & 15;
#pragma unroll
    for (int i = 0; i < 4; ++i)
        *(float4*)&sm[offC + (tm*4 + i) * LDF + tn * 4] =
            make_float4(acc[i][0], acc[i][1], acc[i][2], acc[i][3]);
}

template<bool NEG>
__device__ inline void mmNN32_acc(const float* sm, int offA, int offB,
                                  float (&acc)[4][2], int tid)
{
    const int tm = tid >> 4, tn = tid & 15;
    for (int k0 = 0; k0 < 64; k0 += 4) {
        float4 a[4];
        float2 b[4];
#pragma unroll
        for (int i = 0; i < 4; ++i)
            a[i] = *(const float4*)&sm[offA + (tm*4 + i) * LDF + k0];
#pragma unroll
        for (int q = 0; q < 4; ++q)
            b[q] = *(const float2*)&sm[offB + (k0 + q) * LDH + tn * 2];
#pragma unroll
        for (int i = 0; i < 4; ++i) {
            const float* ap = (const float*)&a[i];
#pragma unroll
            for (int q = 0; q < 4; ++q) {
                const float av = NEG ? -ap[q] : ap[q];
                acc[i][0] = fmaf(av, b[q].x, acc[i][0]);
                acc[i][1] = fmaf(av, b[q].y, acc[i][1]);
            }
        }
    }
}

// ===========================================================================
// Kernel A: per-(chain,chunk) summaries.  grid = P*32, block = 256
// Summary arrays indexed by LOCAL block id; inputs by chainBase + local chain.
// ===========================================================================
__global__ __launch_bounds__(256) void chunk_sum_kernel(
    const float* __restrict__ Qp, const float* __restrict__ Kp,
    const float* __restrict__ Vp, const float* __restrict__ AKp,
    const float* __restrict__ ACp,
    float* __restrict__ ASg, float* __restrict__ ACg,
    float* __restrict__ Mg,  float* __restrict__ AGvg,
    float* __restrict__ DKg, float* __restrict__ DCg,
    int chainBase)
{
    __shared__ float sm[6 * FB];
    const int bid = blockIdx.x, tid = threadIdx.x;
    const int ch = chainBase + (bid >> 5), ck = bid & 31;
    const size_t ib = ((size_t)ch * TT + ck * 64) * 64;

    stage64(sm, 0,      Qp  + ib, tid);
    stage64(sm, FB,     Kp  + ib, tid);
    stage64(sm, 2*FB,   AKp + ib, tid);
    stage64(sm, 3*FB,   ACp + ib, tid);
    stage64(sm, 4*FB,   Vp  + ib, tid);
    __syncthreads();

    if (tid < 128) {
        const int i = tid & 63;
        const int off = (tid < 64) ? 2*FB : 3*FB;
        float p = 1.f;
        for (int t = 0; t < 64; ++t) {
            p *= sm[off + t * LDF + i];
            sm[off + t * LDF + i] = p;
        }
        if (tid < 64) DKg[(size_t)bid * 64 + i] = p;
        else          DCg[(size_t)bid * 64 + i] = p;
    }
    __syncthreads();

    {
        const int row = tid >> 2, cb = (tid & 3) * 16;
        const int sx = (row >> 2) & 7;
#pragma unroll
        for (int w = 0; w < 4; ++w) {
            const int c = cb + w * 4;
            float4 q  = *(const float4*)&sm[0    + row * LDF + c];
            float4 k  = *(const float4*)&sm[FB   + row * LDF + c];
            float4 pk = *(const float4*)&sm[2*FB + row * LDF + c];
            float4 pc = *(const float4*)&sm[3*FB + row * LDF + c];
            *(float4*)&sm[0  + row * LDF + c] = f4mul(k, pc);     // KhC
            *(float4*)&sm[FB + row * LDF + c] = f4div(k, pk);     // Kt
            const int csw = (((c >> 2) ^ sx) << 2);
            *(float4*)&sm[5*FB + row * LDF + csw] = f4div(q, pc); // Qt (sw)
        }
    }
    __syncthreads();

    mmTN_g<false>(sm, FB,   FB,   ASg  + (size_t)bid * 4096, tid); // A_S
    mmTN_g<true >(sm, 5*FB, 4*FB, ACg  + (size_t)bid * 4096, tid); // A_C
    mmTN_g<false>(sm, FB,   0,    Mg   + (size_t)bid * 4096, tid); // M
    mmNT_lds(sm, 0, 5*FB, 2*FB, 2, tid);                           // beta (strict)
    __syncthreads();
    mmNN_lds(sm, 2*FB, 4*FB, 3*FB, tid);                           // T1 = beta*V
    __syncthreads();
    mmTN_g<false>(sm, FB, 3*FB, AGvg + (size_t)bid * 4096, tid);   // A_Gv
}

// ===========================================================================
// Kernel B: sequential chunk-state composition. grid = P, block = 256.
// IN-PLACE: reads summaries A_S/A_C/A_Gv into registers, then overwrites the
// same slots with the BEFORE-chunk states (S0/C0/G0). M stays read-only.
// ===========================================================================
__global__ __launch_bounds__(256) void state_scan_kernel(
    float* __restrict__ ASg, float* __restrict__ ACg,
    const float* __restrict__ Mg,  float* __restrict__ AGvg,
    const float* __restrict__ DKg, const float* __restrict__ DCg)
{
    __shared__ float sm[5 * FB];   // S, C, G, M, MC
    __shared__ float dkv[64], dcv[64];
    const int lch = blockIdx.x, tid = threadIdx.x;

    for (int e = tid; e < 3 * FB; e += 256) sm[e] = 0.f;
    __syncthreads();

    const int row = tid >> 2, c0 = (tid & 3) * 16;

    for (int ck = 0; ck < 32; ++ck) {
        const size_t sb = (size_t)(lch * 32 + ck) * 4096;

        // 1. read summaries into registers; stage M into LDS; gate products
        float4 r_as[4], r_ac[4], r_ag[4];
#pragma unroll
        for (int q = 0; q < 4; ++q) {
            const size_t e = sb + row * 64 + c0 + q * 4;
            r_as[q] = *(const float4*)&ASg[e];
            r_ac[q] = *(const float4*)&ACg[e];
            r_ag[q] = *(const float4*)&AGvg[e];
        }
        stage64(sm, 3 * FB, Mg + sb, tid);
        if (tid < 64)       dkv[tid]      = DKg[(size_t)(lch * 32 + ck) * 64 + tid];
        else if (tid < 128) dcv[tid - 64] = DCg[(size_t)(lch * 32 + ck) * 64 + tid - 64];
        __syncthreads();   // drains vmcnt: regs valid, M staged

        // 2. write before-chunk states into the (aliased) summary slots
#pragma unroll
        for (int q = 0; q < 4; ++q) {
            const int c = c0 + q * 4;
            const size_t e = sb + row * 64 + c;
            *(float4*)&ASg[e]  = *(const float4*)&sm[0    + row * LDF + c];
            *(float4*)&ACg[e]  = *(const float4*)&sm[FB   + row * LDF + c];
            *(float4*)&AGvg[e] = *(const float4*)&sm[2*FB + row * LDF + c];
        }

        // 3. MC = M * C (reads C state, writes 4FB)
        mmNN_lds(sm, 3 * FB, FB, 4 * FB, tid);
        __syncthreads();

        // 4. update states in LDS
        const float dki = dkv[row], dci = dcv[row];
#pragma unroll
        for (int w = 0; w < 4; ++w) {
            const int c = c0 + w * 4;
            float4 dkj = *(const float4*)&dkv[c];
            float4 s   = *(float4*)&sm[0 + row * LDF + c];
            s.x = dki * dkj.x * (s.x + r_as[w].x);
            s.y = dki * dkj.y * (s.y + r_as[w].y);
            s.z = dki * dkj.z * (s.z + r_as[w].z);
            s.w = dki * dkj.w * (s.w + r_as[w].w);
            *(float4*)&sm[0 + row * LDF + c] = s;

            float4 cc = *(float4*)&sm[FB + row * LDF + c];
            cc.x = dci * (cc.x + r_ac[w].x);
            cc.y = dci * (cc.y + r_ac[w].y);
            cc.z = dci * (cc.z + r_ac[w].z);
            cc.w = dci * (cc.w + r_ac[w].w);
            *(float4*)&sm[FB + row * LDF + c] = cc;

            float4 g  = *(float4*)&sm[2*FB + row * LDF + c];
            float4 mc = *(const float4*)&sm[4*FB + row * LDF + c];
            g.x = dki * (g.x + mc.x + r_ag[w].x);
            g.y = dki * (g.y + mc.y + r_ag[w].y);
            g.z = dki * (g.z + mc.z + r_ag[w].z);
            g.w = dki * (g.w + mc.w + r_ag[w].w);
            *(float4*)&sm[2*FB + row * LDF + c] = g;
        }
        __syncthreads();
    }
}

// ===========================================================================
// Kernel C: per-(chain,chunk) outputs. grid = P*32, block = 256.
// States (S0/C0/G0) come from the aliased summary arrays, LOCAL indexing.
// ===========================================================================
__global__ __launch_bounds__(256) void chunk_out_kernel(
    const float* __restrict__ Qp, const float* __restrict__ Kp,
    const float* __restrict__ Vp, const float* __restrict__ AKp,
    const float* __restrict__ ACp,
    const float* __restrict__ S0g, const float* __restrict__ C0g,
    const float* __restrict__ G0g, float* __restrict__ Of,
    int chainBase)
{
    __shared__ float sm[C_POOL];
    const int bid = blockIdx.x, tid = threadIdx.x;
    const int ch = chainBase + (bid >> 5), ck = bid & 31;
    const size_t ib = ((size_t)ch * TT + ck * 64) * 64;

    stage64(sm, C_B0, Qp  + ib, tid);
    stage64(sm, C_B1, Kp  + ib, tid);
    stage64(sm, C_B2, AKp + ib, tid);
    stage64(sm, C_B3, ACp + ib, tid);
    __syncthreads();

    if (tid < 128) {
        const int i = tid & 63;
        const int off = (tid < 64) ? C_B2 : C_B3;
        float p = 1.f;
        for (int t = 0; t < 64; ++t) {
            p *= sm[off + t * LDF + i];
            sm[off + t * LDF + i] = p;
        }
    }
    __syncthreads();

    {
        const int row = tid >> 2, cb = (tid & 3) * 16;
        const int sx = (row >> 2) & 7;
#pragma unroll
        for (int w = 0; w < 4; ++w) {
            const int c = cb + w * 4;
            float4 q  = *(const float4*)&sm[C_B0 + row * LDF + c];
            float4 k  = *(const float4*)&sm[C_B1 + row * LDF + c];
            float4 pk = *(const float4*)&sm[C_B2 + row * LDF + c];
            float4 pc = *(const float4*)&sm[C_B3 + row * LDF + c];
            *(float4*)&sm[C_B0 + row * LDF + c] = f4mul(q, pk);   // Qh
            *(float4*)&sm[C_B1 + row * LDF + c] = f4mul(k, pc);   // KhC
            *(float4*)&sm[C_B2 + row * LDF + c] = f4mul(pk, pc);  // PP
            const int csw = (((c >> 2) ^ sx) << 2);
            *(float4*)&sm[C_B4 + row * LDF + csw] = f4div(q, pc); // Qt (sw)
            *(float4*)&sm[C_B5 + row * LDF + csw] = f4div(k, pk); // Kt (sw)
        }
    }
    __syncthreads();

    stage64(sm, C_B6, S0g + (size_t)bid * 4096, tid);
    mmNT_lds(sm, C_B0, C_B5, C_B3, 1, tid);        // gamma (incl) -> B3
    __syncthreads();

    {   // uh = (Qh*S0 + gamma*Kt) .* PP  -> B7
        float acc[4][4] = {};
        mmNN_acc<false, false>(sm, C_B0, C_B6, acc, tid);
        mmNN_acc<true,  false>(sm, C_B3, C_B5, acc, tid);
        const int tm = tid >> 4, tn = tid & 15;
#pragma unroll
        for (int i = 0; i < 4; ++i) {
            const int m = tm * 4 + i;
            const float4 pp = *(const float4*)&sm[C_B2 + m * LDF + tn * 4];
            *(float4*)&sm[C_B7 + m * LDF + tn * 4] =
                make_float4(acc[i][0] * pp.x, acc[i][1] * pp.y,
                            acc[i][2] * pp.z, acc[i][3] * pp.w);
        }
    }
    __syncthreads();

    mmNT_lds(sm, C_B1, C_B4, C_B2, 2, tid);        // beta (strict) -> B2
    mmNT_lds(sm, C_B7, C_B4, C_B6, 1, tid);        // delta (incl)  -> B6
    __syncthreads();

    const int b_ = ch >> 4, h_ = ch & 15;
    const int tm = tid >> 4, tn = tid & 15;

    for (int vh = 0; vh < 2; ++vh) {
        stage32(sm, C_HV, Vp + ib,                  vh, tid);
        stage32(sm, C_HC, C0g + (size_t)bid * 4096, vh, tid);
        stage32(sm, C_HG, G0g + (size_t)bid * 4096, vh, tid);
        __syncthreads();
        {   // KC half = KhC*C0h + beta*Vh -> HK
            float acc[4][2] = {};
            mmNN32_acc<false>(sm, C_B1, C_HC, acc, tid);
            mmNN32_acc<false>(sm, C_B2, C_HV, acc, tid);
#pragma unroll
            for (int i = 0; i < 4; ++i) {
                sm[C_HK + (tm*4 + i) * LDH + tn*2 + 0] = acc[i][0];
                sm[C_HK + (tm*4 + i) * LDH + tn*2 + 1] = acc[i][1];
            }
        }
        __syncthreads();
        {   // O half = uh*C0h + delta*Vh - Qh*G0h - gamma*KCh
            float acc[4][2] = {};
            mmNN32_acc<false>(sm, C_B7, C_HC, acc, tid);
            mmNN32_acc<false>(sm, C_B6, C_HV, acc, tid);
            mmNN32_acc<true >(sm, C_B0, C_HG, acc, tid);
            mmNN32_acc<true >(sm, C_B3, C_HK, acc, tid);
#pragma unroll
            for (int i = 0; i < 4; ++i) {
                const int t = ck * 64 + tm * 4 + i;
                const size_t o = ((size_t)b_ * TT + t) * 1024 + h_ * 64 + vh * 32 + tn * 2;
                *(float2*)&Of[o] = make_float2(acc[i][0], acc[i][1]);
            }
        }
        __syncthreads();
    }
}

// ===========================================================================
// Fallback: round-1 sequential scan (only if even P=4 doesn't fit)
// ===========================================================================
__global__ __launch_bounds__(256) void scan_kernel(
    const float* __restrict__ Q,  const float* __restrict__ Kv,
    const float* __restrict__ V,  const float* __restrict__ AK,
    const float* __restrict__ AC, float* __restrict__ Oflat)
{
    const int bh  = blockIdx.x;
    const int b_  = bh >> 4;
    const int h_  = bh & 15;
    const int tid = threadIdx.x;
    const int c   = tid >> 2;
    const int r4  = tid & 3;
    const int i0  = r4 * 16;

    __shared__ __align__(16) float vals[2][5][64];
    __shared__ __align__(16) float u_lds[64];

    const size_t base = (size_t)bh * TT * 64;
    const float* arrs[5] = {Q + base, Kv + base, V + base, AK + base, AC + base};

    float sk[16], cv[16], g[16];
#pragma unroll
    for (int r = 0; r < 16; ++r) { sk[r] = 0.f; cv[r] = 0.f; g[r] = 0.f; }

    const bool loader = (tid < 80);
    const int  larr = tid >> 4;
    const int  loff = (tid & 15) * 4;
    float4 pf[2];

    if (loader) {
        pf[0] = *(const float4*)(arrs[larr] + 0 * 64 + loff);
        pf[1] = *(const float4*)(arrs[larr] + 1 * 64 + loff);
        *(float4*)&vals[0][larr][loff] = pf[0];
    }
    __syncthreads();

    for (int t = 0; t < TT; ++t) {
        const int cur = t & 1;
        if (loader && (t + 2) < TT)
            pf[cur] = *(const float4*)(arrs[larr] + (size_t)(t + 2) * 64 + loff);

        float qv[16], kv[16], ak[16], ac[16];
#pragma unroll
        for (int r = 0; r < 16; r += 4) {
            *(float4*)&qv[r] = *(const float4*)&vals[cur][0][i0 + r];
            *(float4*)&kv[r] = *(const float4*)&vals[cur][1][i0 + r];
            *(float4*)&ak[r] = *(const float4*)&vals[cur][3][i0 + r];
            *(float4*)&ac[r] = *(const float4*)&vals[cur][4][i0 + r];
        }
        const float vc  = vals[cur][2][c];
        const float kc  = vals[cur][1][c];
        const float akc = vals[cur][3][c];

        float pk[4] = {0.f, 0.f, 0.f, 0.f};
#pragma unroll
        for (int r = 0; r < 16; ++r) {
            const float s = ac[r] * cv[r];
            pk[r & 3] = fmaf(kv[r], s, pk[r & 3]);
            cv[r] = fmaf(qv[r], vc, s);
        }
        float ktc = (pk[0] + pk[1]) + (pk[2] + pk[3]);
        ktc += __shfl_xor(ktc, 1);
        ktc += __shfl_xor(ktc, 2);

        float pu[4] = {0.f, 0.f, 0.f, 0.f};
        float pw[4] = {0.f, 0.f, 0.f, 0.f};
#pragma unroll
        for (int r = 0; r < 16; ++r) {
            g[r]  = fmaf(ak[r], g[r], kv[r] * ktc);
            sk[r] = fmaf(ak[r] * akc, sk[r], kv[r] * kc);
            pu[r & 3] = fmaf(qv[r], sk[r], pu[r & 3]);
            pw[r & 3] = fmaf(qv[r], g[r],  pw[r & 3]);
        }
        float u = (pu[0] + pu[1]) + (pu[2] + pu[3]);
        u += __shfl_xor(u, 1);
        u += __shfl_xor(u, 2);
        float w = (pw[0] + pw[1]) + (pw[2] + pw[3]);
        w += __shfl_xor(w, 1);
        w += __shfl_xor(w, 2);

        if (r4 == 0) u_lds[c] = u;
        __syncthreads();

        float po[4] = {0.f, 0.f, 0.f, 0.f};
#pragma unroll
        for (int r = 0; r < 16; r += 4) {
            const float4 uu = *(const float4*)&u_lds[i0 + r];
            po[0] = fmaf(uu.x, cv[r + 0], po[0]);
            po[1] = fmaf(uu.y, cv[r + 1], po[1]);
            po[2] = fmaf(uu.z, cv[r + 2], po[2]);
            po[3] = fmaf(uu.w, cv[r + 3], po[3]);
        }
        float o = (po[0] + po[1]) + (po[2] + po[3]);
        o += __shfl_xor(o, 1);
        o += __shfl_xor(o, 2);

        if (r4 == 0)
            Oflat[((size_t)b_ * TT + t) * 1024 + h_ * 64 + c] = o - w;

        if (loader && (t + 1) < TT)
            *(float4*)&vals[cur ^ 1][larr][loff] = pf[cur ^ 1];
        __syncthreads();
    }
}

// ===========================================================================
extern "C" void kernel_launch(void* const* d_in, const int* in_sizes, int n_in,
                              void* d_out, int out_size, void* d_ws, size_t ws_size,
                              hipStream_t stream)
{
    const float* x    = (const float*)d_in[0];
    const float* W_q  = (const float*)d_in[1];
    const float* W_k  = (const float*)d_in[2];
    const float* W_v  = (const float*)d_in[3];
    const float* Wg_K = (const float*)d_in[4];
    const float* bg_K = (const float*)d_in[5];
    const float* Wg_C = (const float*)d_in[6];
    const float* bg_C = (const float*)d_in[7];
    const float* W_o  = (const float*)d_in[8];

    float* ws = (float*)d_ws;
    const size_t S1 = (size_t)BB * NH * TT * 64;   // 8,388,608 floats
    float* Qp = ws + 0 * S1;
    float* Kp = ws + 1 * S1;
    float* Vp = ws + 2 * S1;
    float* AK = ws + 3 * S1;
    float* AC = ws + 4 * S1;
    float* Of = ws + 5 * S1;

    dim3 grid(BT / 128, 1024 / 128);
    dim3 blk(256);

    gemm_kernel<<<grid, blk, 0, stream>>>(x, W_q,  nullptr, Qp, 0);
    gemm_kernel<<<grid, blk, 0, stream>>>(x, W_k,  nullptr, Kp, 0);
    gemm_kernel<<<grid, blk, 0, stream>>>(x, W_v,  nullptr, Vp, 0);
    gemm_kernel<<<grid, blk, 0, stream>>>(x, Wg_K, bg_K,    AK, 1);
    gemm_kernel<<<grid, blk, 0, stream>>>(x, Wg_C, bg_C,    AC, 1);

    // adaptive pass size: largest P (chains per pass) whose buffers fit
    const size_t availF = (ws_size / 4 > 6 * S1) ? (ws_size / 4 - 6 * S1) : 0;
    int P = 0;
    for (int cand = 64; cand >= 4; cand >>= 1) {
        const size_t ex = (size_t)cand * 32 * 4096 * 4 + (size_t)cand * 32 * 64 * 2;
        if (availF >= ex) { P = cand; break; }
    }

    if (P > 0) {
        const size_t CS = (size_t)P * 32 * 4096;
        float* ASg  = ws + 6 * S1;        // becomes S0 after kernel B
        float* ACg  = ASg + CS;           // becomes C0
        float* Mg   = ACg + CS;
        float* AGvg = Mg  + CS;           // becomes G0
        float* DKg  = AGvg + CS;
        float* DCg  = DKg + (size_t)P * 32 * 64;

        for (int p0 = 0; p0 < 64; p0 += P) {
            chunk_sum_kernel<<<dim3(P * 32), blk, 0, stream>>>(
                Qp, Kp, Vp, AK, AC, ASg, ACg, Mg, AGvg, DKg, DCg, p0);
            state_scan_kernel<<<dim3(P), blk, 0, stream>>>(
                ASg, ACg, Mg, AGvg, DKg, DCg);
            chunk_out_kernel<<<dim3(P * 32), blk, 0, stream>>>(
                Qp, Kp, Vp, AK, AC, ASg, ACg, AGvg, Of, p0);
        }
    } else {
        scan_kernel<<<dim3(64), blk, 0, stream>>>(Qp, Kp, Vp, AK, AC, Of);
    }

    gemm_kernel<<<grid, blk, 0, stream>>>(Of, W_o, nullptr, (float*)d_out, 2);
}

// Round 5
// 1408.771 us; speedup vs baseline: 2.6797x; 1.7567x over previous
//
#include <hip/hip_runtime.h>
#include <hip/hip_bf16.h>

#define DMODEL 1024
#define NH     16
#define BB     4
#define TT     2048
#define BT     (BB * TT)   // 8192

typedef __bf16 bf16_t;
typedef __attribute__((ext_vector_type(8))) __bf16 bf16x8;
typedef __attribute__((ext_vector_type(4))) float f32x4;

// chunked-scan geometry
#define LDF    68
#define FB     4352
#define LDH    36
#define HB     2304

#define C_B0   0
#define C_B1   FB
#define C_B2   (2*FB)
#define C_B3   (3*FB)
#define C_B4   (4*FB)
#define C_B5   (5*FB)
#define C_HV   (4*FB)
#define C_HC   (4*FB + HB)
#define C_HG   (4*FB + 2*HB)
#define C_HK   (4*FB + 3*HB)
#define C_B6   (4*FB + 4*HB)
#define C_B7   (C_B6 + FB)
#define C_POOL (C_B7 + FB)

// ===========================================================================
// Weight prep: W[k][n] fp32 -> Wt[n][k] bf16, 1024x1024, grid (16,16,6)
// ===========================================================================
__global__ __launch_bounds__(256) void wprep_kernel(
    const float* __restrict__ w0, const float* __restrict__ w1,
    const float* __restrict__ w2, const float* __restrict__ w3,
    const float* __restrict__ w4, const float* __restrict__ w5,
    bf16_t* __restrict__ d0, bf16_t* __restrict__ d1,
    bf16_t* __restrict__ d2, bf16_t* __restrict__ d3,
    bf16_t* __restrict__ d4, bf16_t* __restrict__ d5)
{
    __shared__ float tile[64][65];
    const float* src; bf16_t* dst;
    switch (blockIdx.z) {
        case 0: src = w0; dst = d0; break;
        case 1: src = w1; dst = d1; break;
        case 2: src = w2; dst = d2; break;
        case 3: src = w3; dst = d3; break;
        case 4: src = w4; dst = d4; break;
        default: src = w5; dst = d5; break;
    }
    const int k0 = blockIdx.x * 64, n0 = blockIdx.y * 64;
    const int tid = threadIdx.x;
    const int r = tid >> 2, c = (tid & 3) * 16;
#pragma unroll
    for (int q = 0; q < 4; ++q)
        *(float4*)&tile[r][c + q * 4] =
            *(const float4*)&src[(size_t)(k0 + r) * 1024 + n0 + c + q * 4];
    __syncthreads();
    const int rn = tid >> 2, ck = (tid & 3) * 16;
    bf16x8 h0, h1;
#pragma unroll
    for (int j = 0; j < 8; ++j) h0[j] = (bf16_t)tile[ck + j][rn];
#pragma unroll
    for (int j = 0; j < 8; ++j) h1[j] = (bf16_t)tile[ck + 8 + j][rn];
    *(bf16x8*)&dst[(size_t)(n0 + rn) * 1024 + k0 + ck]     = h0;
    *(bf16x8*)&dst[(size_t)(n0 + rn) * 1024 + k0 + ck + 8] = h1;
}

// ===========================================================================
// bf16 MFMA GEMM: out(8192x1024) = A(8192x1024 fp32, converted) * Wt^T
// Wt is [n][k] bf16 (pre-transposed). 128x128 tile, BK=32, 4 waves 2x2.
// mode 0: proj layout; mode 1: proj + sigmoid(x+bias); mode 2: row-major.
// ===========================================================================
__global__ __launch_bounds__(256) void gemm_bf16_kernel(
    const float* __restrict__ A, const bf16_t* __restrict__ Bt,
    const float* __restrict__ bias, float* __restrict__ out, int mode)
{
    __shared__ __align__(16) bf16_t Asm[128][48];
    __shared__ __align__(16) bf16_t Bsm[128][48];

    const int tid  = threadIdx.x;
    const int lane = tid & 63, wave = tid >> 6;
    const int wr = (wave >> 1) * 64, wc = (wave & 1) * 64;
    const int l15 = lane & 15, l16 = lane >> 4;
    const int m0 = blockIdx.x * 128, n0 = blockIdx.y * 128;

    const int srow = tid >> 1, scol = (tid & 1) * 16;
    const float*  aptr = A  + (size_t)(m0 + srow) * 1024 + scol;
    const bf16_t* bptr = Bt + (size_t)(n0 + srow) * 1024 + scol;

    f32x4 acc[4][4];
#pragma unroll
    for (int i = 0; i < 4; ++i)
#pragma unroll
        for (int j = 0; j < 4; ++j) acc[i][j] = (f32x4){0.f, 0.f, 0.f, 0.f};

    float4 va[4];
    bf16x8 vb[2];
#pragma unroll
    for (int q = 0; q < 4; ++q) va[q] = *(const float4*)(aptr + q * 4);
    vb[0] = *(const bf16x8*)(bptr);
    vb[1] = *(const bf16x8*)(bptr + 8);

    for (int k0 = 0; k0 < 1024; k0 += 32) {
        __syncthreads();
        {
            bf16x8 h0, h1;
            h0[0]=(bf16_t)va[0].x; h0[1]=(bf16_t)va[0].y; h0[2]=(bf16_t)va[0].z; h0[3]=(bf16_t)va[0].w;
            h0[4]=(bf16_t)va[1].x; h0[5]=(bf16_t)va[1].y; h0[6]=(bf16_t)va[1].z; h0[7]=(bf16_t)va[1].w;
            h1[0]=(bf16_t)va[2].x; h1[1]=(bf16_t)va[2].y; h1[2]=(bf16_t)va[2].z; h1[3]=(bf16_t)va[2].w;
            h1[4]=(bf16_t)va[3].x; h1[5]=(bf16_t)va[3].y; h1[6]=(bf16_t)va[3].z; h1[7]=(bf16_t)va[3].w;
            *(bf16x8*)&Asm[srow][scol]     = h0;
            *(bf16x8*)&Asm[srow][scol + 8] = h1;
            *(bf16x8*)&Bsm[srow][scol]     = vb[0];
            *(bf16x8*)&Bsm[srow][scol + 8] = vb[1];
        }
        __syncthreads();
        if (k0 + 32 < 1024) {
#pragma unroll
            for (int q = 0; q < 4; ++q)
                va[q] = *(const float4*)(aptr + k0 + 32 + q * 4);
            vb[0] = *(const bf16x8*)(bptr + k0 + 32);
            vb[1] = *(const bf16x8*)(bptr + k0 + 40);
        }
        bf16x8 af[4], bfr[4];
#pragma unroll
        for (int m = 0; m < 4; ++m)
            af[m] = *(const bf16x8*)&Asm[wr + m * 16 + l15][l16 * 8];
#pragma unroll
        for (int n = 0; n < 4; ++n)
            bfr[n] = *(const bf16x8*)&Bsm[wc + n * 16 + l15][l16 * 8];
#pragma unroll
        for (int m = 0; m < 4; ++m)
#pragma unroll
            for (int n = 0; n < 4; ++n)
                acc[m][n] = __builtin_amdgcn_mfma_f32_16x16x32_bf16(
                    af[m], bfr[n], acc[m][n], 0, 0, 0);
    }

    // epilogue: C/D layout col = lane&15, row = (lane>>4)*4 + reg  [m89]
#pragma unroll
    for (int n = 0; n < 4; ++n) {
        const int col = n0 + wc + n * 16 + l15;
        const int h = col >> 6, d = col & 63;
        const float bb = (mode == 1) ? bias[col] : 0.f;
#pragma unroll
        for (int m = 0; m < 4; ++m) {
#pragma unroll
            for (int r = 0; r < 4; ++r) {
                const int row = m0 + wr + m * 16 + l16 * 4 + r;
                float v = acc[m][n][r];
                if (mode == 2) {
                    out[(size_t)row * 1024 + col] = v;
                } else {
                    if (mode == 1) v = 1.f / (1.f + expf(-(v + bb)));
                    const int b_ = row >> 11, t_ = row & 2047;
                    out[((size_t)((b_ * NH + h) * TT + t_) << 6) + d] = v;
                }
            }
        }
    }
}

// ===========================================================================
// fp32 tiled GEMM (fallback path only)
// ===========================================================================
__global__ __launch_bounds__(256) void gemm_kernel(
    const float* __restrict__ A,
    const float* __restrict__ Bw,
    const float* __restrict__ bias,
    float* __restrict__ out,
    int mode)
{
    __shared__ __align__(16) float As[16][132];
    __shared__ __align__(16) float Bs[16][132];

    const int tid = threadIdx.x;
    const int tm = tid >> 4;
    const int tn = tid & 15;
    const int m0 = blockIdx.x * 128;
    const int n0 = blockIdx.y * 128;

    float acc[8][8];
#pragma unroll
    for (int i = 0; i < 8; ++i)
#pragma unroll
        for (int j = 0; j < 8; ++j) acc[i][j] = 0.f;

    const int arow = tid >> 2;
    const int akq  = (tid & 3) * 4;
    const int brow = tid >> 5;
    const int bnq  = (tid & 31) * 4;

    for (int k0 = 0; k0 < 1024; k0 += 16) {
#pragma unroll
        for (int it = 0; it < 2; ++it) {
            const int mr = it * 64 + arow;
            const float4 va = *(const float4*)(A + (size_t)(m0 + mr) * 1024 + k0 + akq);
            As[akq + 0][mr] = va.x;
            As[akq + 1][mr] = va.y;
            As[akq + 2][mr] = va.z;
            As[akq + 3][mr] = va.w;
        }
#pragma unroll
        for (int it = 0; it < 2; ++it) {
            const int kr = it * 8 + brow;
            const float4 vb = *(const float4*)(Bw + (size_t)(k0 + kr) * 1024 + n0 + bnq);
            *(float4*)&Bs[kr][bnq] = vb;
        }
        __syncthreads();
#pragma unroll
        for (int k = 0; k < 16; ++k) {
            float a[8], b[8];
            *(float4*)&a[0] = *(const float4*)&As[k][tm * 8];
            *(float4*)&a[4] = *(const float4*)&As[k][tm * 8 + 4];
            *(float4*)&b[0] = *(const float4*)&Bs[k][tn * 8];
            *(float4*)&b[4] = *(const float4*)&Bs[k][tn * 8 + 4];
#pragma unroll
            for (int i = 0; i < 8; ++i)
#pragma unroll
                for (int j = 0; j < 8; ++j)
                    acc[i][j] = fmaf(a[i], b[j], acc[i][j]);
        }
        __syncthreads();
    }

    if (mode == 2) {
#pragma unroll
        for (int i = 0; i < 8; ++i) {
            const int m = m0 + tm * 8 + i;
            float* dst = out + (size_t)m * 1024 + n0 + tn * 8;
            *(float4*)dst       = make_float4(acc[i][0], acc[i][1], acc[i][2], acc[i][3]);
            *((float4*)dst + 1) = make_float4(acc[i][4], acc[i][5], acc[i][6], acc[i][7]);
        }
    } else {
        const int nn = n0 + tn * 8;
        const int h = nn >> 6;
        const int d = nn & 63;
        float bb[8];
        if (mode == 1) {
#pragma unroll
            for (int j = 0; j < 8; ++j) bb[j] = bias[nn + j];
        }
#pragma unroll
        for (int i = 0; i < 8; ++i) {
            const int m  = m0 + tm * 8 + i;
            const int b_ = m >> 11;
            const int t_ = m & 2047;
            float v[8];
#pragma unroll
            for (int j = 0; j < 8; ++j) {
                float x = acc[i][j];
                if (mode == 1) x = 1.f / (1.f + expf(-(x + bb[j])));
                v[j] = x;
            }
            float* dst = out + ((size_t)((b_ * NH + h) * TT + t_) << 6) + d;
            *(float4*)dst       = make_float4(v[0], v[1], v[2], v[3]);
            *((float4*)dst + 1) = make_float4(v[4], v[5], v[6], v[7]);
        }
    }
}

// ===========================================================================
// chunked-path helpers
// ===========================================================================
__device__ inline float4 f4mul(float4 a, float4 b) {
    return make_float4(a.x*b.x, a.y*b.y, a.z*b.z, a.w*b.w);
}
__device__ inline float4 f4div(float4 a, float4 b) {
    return make_float4(a.x/b.x, a.y/b.y, a.z/b.z, a.w/b.w);
}

__device__ inline void stage64(float* sm, int off, const float* __restrict__ g, int tid)
{
    const int row = tid >> 2, c0 = (tid & 3) * 16;
#pragma unroll
    for (int q = 0; q < 4; ++q) {
        float4 v = *(const float4*)&g[(size_t)row * 64 + c0 + q * 4];
        *(float4*)&sm[off + row * LDF + c0 + q * 4] = v;
    }
}

__device__ inline void stage32(float* sm, int off, const float* __restrict__ g, int vh, int tid)
{
    const int row = tid >> 2, c0 = (tid & 3) * 8;
#pragma unroll
    for (int q = 0; q < 2; ++q) {
        float4 v = *(const float4*)&g[(size_t)row * 64 + vh * 32 + c0 + q * 4];
        *(float4*)&sm[off + row * LDH + c0 + q * 4] = v;
    }
}

template<bool SWA>
__device__ inline void mmTN_g(const float* sm, int offA, int offB,
                              float* __restrict__ gout, int tid)
{
    const int tm = tid >> 4, tn = tid & 15;
    float acc[4][4] = {};
    for (int k0 = 0; k0 < 64; k0 += 4) {
        float4 a[4], b[4];
#pragma unroll
        for (int q = 0; q < 4; ++q) {
            const int row = k0 + q;
            const int ca = SWA ? (tm ^ ((row >> 2) & 7)) : tm;
            a[q] = *(const float4*)&sm[offA + row * LDF + ca * 4];
            b[q] = *(const float4*)&sm[offB + row * LDF + tn * 4];
        }
#pragma unroll
        for (int q = 0; q < 4; ++q) {
            const float* ap = (const float*)&a[q];
            const float* bp = (const float*)&b[q];
#pragma unroll
            for (int i = 0; i < 4; ++i)
#pragma unroll
                for (int j = 0; j < 4; ++j)
                    acc[i][j] = fmaf(ap[i], bp[j], acc[i][j]);
        }
    }
#pragma unroll
    for (int i = 0; i < 4; ++i)
        *(float4*)&gout[(size_t)(tm*4 + i) * 64 + tn * 4] =
            make_float4(acc[i][0], acc[i][1], acc[i][2], acc[i][3]);
}

__device__ inline void mmNT_lds(float* sm, int offA, int offB, int offC,
                                int mask, int tid)
{
    const int tm = tid >> 4, tn = tid & 15;
    float acc[4][4] = {};
    for (int k0 = 0; k0 < 64; k0 += 4) {
        float4 a[4], b[4];
#pragma unroll
        for (int i = 0; i < 4; ++i)
            a[i] = *(const float4*)&sm[offA + (tm*4 + i) * LDF + k0];
        const int cc = ((k0 >> 2) ^ (tn & 7)) * 4;
#pragma unroll
        for (int j = 0; j < 4; ++j)
            b[j] = *(const float4*)&sm[offB + (tn*4 + j) * LDF + cc];
#pragma unroll
        for (int i = 0; i < 4; ++i) {
            const float* ap = (const float*)&a[i];
#pragma unroll
            for (int j = 0; j < 4; ++j) {
                const float* bp = (const float*)&b[j];
                acc[i][j] = fmaf(ap[0], bp[0], acc[i][j]);
                acc[i][j] = fmaf(ap[1], bp[1], acc[i][j]);
                acc[i][j] = fmaf(ap[2], bp[2], acc[i][j]);
                acc[i][j] = fmaf(ap[3], bp[3], acc[i][j]);
            }
        }
    }
#pragma unroll
    for (int i = 0; i < 4; ++i) {
        const int m = tm*4 + i;
#pragma unroll
        for (int j = 0; j < 4; ++j) {
            const int n = tn*4 + j;
            float v = acc[i][j];
            if (mask == 1 && n > m)  v = 0.f;
            if (mask == 2 && n >= m) v = 0.f;
            sm[offC + m * LDF + n] = v;
        }
    }
}

template<bool SWB, bool NEG>
__device__ inline void mmNN_acc(const float* sm, int offA, int offB,
                                float (&acc)[4][4], int tid)
{
    const int tm = tid >> 4, tn = tid & 15;
    for (int k0 = 0; k0 < 64; k0 += 4) {
        float4 a[4], b[4];
#pragma unroll
        for (int i = 0; i < 4; ++i)
            a[i] = *(const float4*)&sm[offA + (tm*4 + i) * LDF + k0];
        const int ctn = SWB ? ((tn ^ ((k0 >> 2) & 7)) * 4) : (tn * 4);
#pragma unroll
        for (int q = 0; q < 4; ++q)
            b[q] = *(const float4*)&sm[offB + (k0 + q) * LDF + ctn];
#pragma unroll
        for (int i = 0; i < 4; ++i) {
            const float* ap = (const float*)&a[i];
#pragma unroll
            for (int q = 0; q < 4; ++q) {
                const float av = NEG ? -ap[q] : ap[q];
                const float* bp = (const float*)&b[q];
#pragma unroll
                for (int j = 0; j < 4; ++j)
                    acc[i][j] = fmaf(av, bp[j], acc[i][j]);
            }
        }
    }
}

__device__ inline void mmNN_lds(float* sm, int offA, int offB, int offC, int tid)
{
    float acc[4][4] = {};
    mmNN_acc<false, false>(sm, offA, offB, acc, tid);
    const int tm = tid >> 4, tn = tid & 15;
#pragma unroll
    for (int i = 0; i < 4; ++i)
        *(float4*)&sm[offC + (tm*4 + i) * LDF + tn * 4] =
            make_float4(acc[i][0], acc[i][1], acc[i][2], acc[i][3]);
}

template<bool NEG>
__device__ inline void mmNN32_acc(const float* sm, int offA, int offB,
                                  float (&acc)[4][2], int tid)
{
    const int tm = tid >> 4, tn = tid & 15;
    for (int k0 = 0; k0 < 64; k0 += 4) {
        float4 a[4];
        float2 b[4];
#pragma unroll
        for (int i = 0; i < 4; ++i)
            a[i] = *(const float4*)&sm[offA + (tm*4 + i) * LDF + k0];
#pragma unroll
        for (int q = 0; q < 4; ++q)
            b[q] = *(const float2*)&sm[offB + (k0 + q) * LDH + tn * 2];
#pragma unroll
        for (int i = 0; i < 4; ++i) {
            const float* ap = (const float*)&a[i];
#pragma unroll
            for (int q = 0; q < 4; ++q) {
                const float av = NEG ? -ap[q] : ap[q];
                acc[i][0] = fmaf(av, b[q].x, acc[i][0]);
                acc[i][1] = fmaf(av, b[q].y, acc[i][1]);
            }
        }
    }
}

// ===========================================================================
// Kernel A: per-(chain,chunk) summaries
// ===========================================================================
__global__ __launch_bounds__(256) void chunk_sum_kernel(
    const float* __restrict__ Qp, const float* __restrict__ Kp,
    const float* __restrict__ Vp, const float* __restrict__ AKp,
    const float* __restrict__ ACp,
    float* __restrict__ ASg, float* __restrict__ ACg,
    float* __restrict__ Mg,  float* __restrict__ AGvg,
    float* __restrict__ DKg, float* __restrict__ DCg,
    int chainBase)
{
    __shared__ float sm[6 * FB];
    const int bid = blockIdx.x, tid = threadIdx.x;
    const int ch = chainBase + (bid >> 5), ck = bid & 31;
    const size_t ib = ((size_t)ch * TT + ck * 64) * 64;

    stage64(sm, 0,      Qp  + ib, tid);
    stage64(sm, FB,     Kp  + ib, tid);
    stage64(sm, 2*FB,   AKp + ib, tid);
    stage64(sm, 3*FB,   ACp + ib, tid);
    stage64(sm, 4*FB,   Vp  + ib, tid);
    __syncthreads();

    if (tid < 128) {
        const int i = tid & 63;
        const int off = (tid < 64) ? 2*FB : 3*FB;
        float p = 1.f;
        for (int t = 0; t < 64; ++t) {
            p *= sm[off + t * LDF + i];
            sm[off + t * LDF + i] = p;
        }
        if (tid < 64) DKg[(size_t)bid * 64 + i] = p;
        else          DCg[(size_t)bid * 64 + i] = p;
    }
    __syncthreads();

    {
        const int row = tid >> 2, cb = (tid & 3) * 16;
        const int sx = (row >> 2) & 7;
#pragma unroll
        for (int w = 0; w < 4; ++w) {
            const int c = cb + w * 4;
            float4 q  = *(const float4*)&sm[0    + row * LDF + c];
            float4 k  = *(const float4*)&sm[FB   + row * LDF + c];
            float4 pk = *(const float4*)&sm[2*FB + row * LDF + c];
            float4 pc = *(const float4*)&sm[3*FB + row * LDF + c];
            *(float4*)&sm[0  + row * LDF + c] = f4mul(k, pc);
            *(float4*)&sm[FB + row * LDF + c] = f4div(k, pk);
            const int csw = (((c >> 2) ^ sx) << 2);
            *(float4*)&sm[5*FB + row * LDF + csw] = f4div(q, pc);
        }
    }
    __syncthreads();

    mmTN_g<false>(sm, FB,   FB,   ASg  + (size_t)bid * 4096, tid);
    mmTN_g<true >(sm, 5*FB, 4*FB, ACg  + (size_t)bid * 4096, tid);
    mmTN_g<false>(sm, FB,   0,    Mg   + (size_t)bid * 4096, tid);
    mmNT_lds(sm, 0, 5*FB, 2*FB, 2, tid);
    __syncthreads();
    mmNN_lds(sm, 2*FB, 4*FB, 3*FB, tid);
    __syncthreads();
    mmTN_g<false>(sm, FB, 3*FB, AGvg + (size_t)bid * 4096, tid);
}

// ===========================================================================
// Kernel B: sequential chunk-state composition (in-place aliasing)
// ===========================================================================
__global__ __launch_bounds__(256) void state_scan_kernel(
    float* __restrict__ ASg, float* __restrict__ ACg,
    const float* __restrict__ Mg,  float* __restrict__ AGvg,
    const float* __restrict__ DKg, const float* __restrict__ DCg)
{
    __shared__ float sm[5 * FB];
    __shared__ float dkv[64], dcv[64];
    const int lch = blockIdx.x, tid = threadIdx.x;

    for (int e = tid; e < 3 * FB; e += 256) sm[e] = 0.f;
    __syncthreads();

    const int row = tid >> 2, c0 = (tid & 3) * 16;

    for (int ck = 0; ck < 32; ++ck) {
        const size_t sb = (size_t)(lch * 32 + ck) * 4096;

        float4 r_as[4], r_ac[4], r_ag[4];
#pragma unroll
        for (int q = 0; q < 4; ++q) {
            const size_t e = sb + row * 64 + c0 + q * 4;
            r_as[q] = *(const float4*)&ASg[e];
            r_ac[q] = *(const float4*)&ACg[e];
            r_ag[q] = *(const float4*)&AGvg[e];
        }
        stage64(sm, 3 * FB, Mg + sb, tid);
        if (tid < 64)       dkv[tid]      = DKg[(size_t)(lch * 32 + ck) * 64 + tid];
        else if (tid < 128) dcv[tid - 64] = DCg[(size_t)(lch * 32 + ck) * 64 + tid - 64];
        __syncthreads();

#pragma unroll
        for (int q = 0; q < 4; ++q) {
            const int c = c0 + q * 4;
            const size_t e = sb + row * 64 + c;
            *(float4*)&ASg[e]  = *(const float4*)&sm[0    + row * LDF + c];
            *(float4*)&ACg[e]  = *(const float4*)&sm[FB   + row * LDF + c];
            *(float4*)&AGvg[e] = *(const float4*)&sm[2*FB + row * LDF + c];
        }

        mmNN_lds(sm, 3 * FB, FB, 4 * FB, tid);
        __syncthreads();

        const float dki = dkv[row], dci = dcv[row];
#pragma unroll
        for (int w = 0; w < 4; ++w) {
            const int c = c0 + w * 4;
            float4 dkj = *(const float4*)&dkv[c];
            float4 s   = *(float4*)&sm[0 + row * LDF + c];
            s.x = dki * dkj.x * (s.x + r_as[w].x);
            s.y = dki * dkj.y * (s.y + r_as[w].y);
            s.z = dki * dkj.z * (s.z + r_as[w].z);
            s.w = dki * dkj.w * (s.w + r_as[w].w);
            *(float4*)&sm[0 + row * LDF + c] = s;

            float4 cc = *(float4*)&sm[FB + row * LDF + c];
            cc.x = dci * (cc.x + r_ac[w].x);
            cc.y = dci * (cc.y + r_ac[w].y);
            cc.z = dci * (cc.z + r_ac[w].z);
            cc.w = dci * (cc.w + r_ac[w].w);
            *(float4*)&sm[FB + row * LDF + c] = cc;

            float4 g  = *(float4*)&sm[2*FB + row * LDF + c];
            float4 mc = *(const float4*)&sm[4*FB + row * LDF + c];
            g.x = dki * (g.x + mc.x + r_ag[w].x);
            g.y = dki * (g.y + mc.y + r_ag[w].y);
            g.z = dki * (g.z + mc.z + r_ag[w].z);
            g.w = dki * (g.w + mc.w + r_ag[w].w);
            *(float4*)&sm[2*FB + row * LDF + c] = g;
        }
        __syncthreads();
    }
}

// ===========================================================================
// Kernel C: per-(chain,chunk) outputs
// ===========================================================================
__global__ __launch_bounds__(256) void chunk_out_kernel(
    const float* __restrict__ Qp, const float* __restrict__ Kp,
    const float* __restrict__ Vp, const float* __restrict__ AKp,
    const float* __restrict__ ACp,
    const float* __restrict__ S0g, const float* __restrict__ C0g,
    const float* __restrict__ G0g, float* __restrict__ Of,
    int chainBase)
{
    __shared__ float sm[C_POOL];
    const int bid = blockIdx.x, tid = threadIdx.x;
    const int ch = chainBase + (bid >> 5), ck = bid & 31;
    const size_t ib = ((size_t)ch * TT + ck * 64) * 64;

    stage64(sm, C_B0, Qp  + ib, tid);
    stage64(sm, C_B1, Kp  + ib, tid);
    stage64(sm, C_B2, AKp + ib, tid);
    stage64(sm, C_B3, ACp + ib, tid);
    __syncthreads();

    if (tid < 128) {
        const int i = tid & 63;
        const int off = (tid < 64) ? C_B2 : C_B3;
        float p = 1.f;
        for (int t = 0; t < 64; ++t) {
            p *= sm[off + t * LDF + i];
            sm[off + t * LDF + i] = p;
        }
    }
    __syncthreads();

    {
        const int row = tid >> 2, cb = (tid & 3) * 16;
        const int sx = (row >> 2) & 7;
#pragma unroll
        for (int w = 0; w < 4; ++w) {
            const int c = cb + w * 4;
            float4 q  = *(const float4*)&sm[C_B0 + row * LDF + c];
            float4 k  = *(const float4*)&sm[C_B1 + row * LDF + c];
            float4 pk = *(const float4*)&sm[C_B2 + row * LDF + c];
            float4 pc = *(const float4*)&sm[C_B3 + row * LDF + c];
            *(float4*)&sm[C_B0 + row * LDF + c] = f4mul(q, pk);
            *(float4*)&sm[C_B1 + row * LDF + c] = f4mul(k, pc);
            *(float4*)&sm[C_B2 + row * LDF + c] = f4mul(pk, pc);
            const int csw = (((c >> 2) ^ sx) << 2);
            *(float4*)&sm[C_B4 + row * LDF + csw] = f4div(q, pc);
            *(float4*)&sm[C_B5 + row * LDF + csw] = f4div(k, pk);
        }
    }
    __syncthreads();

    stage64(sm, C_B6, S0g + (size_t)bid * 4096, tid);
    mmNT_lds(sm, C_B0, C_B5, C_B3, 1, tid);
    __syncthreads();

    {
        float acc[4][4] = {};
        mmNN_acc<false, false>(sm, C_B0, C_B6, acc, tid);
        mmNN_acc<true,  false>(sm, C_B3, C_B5, acc, tid);
        const int tm = tid >> 4, tn = tid & 15;
#pragma unroll
        for (int i = 0; i < 4; ++i) {
            const int m = tm * 4 + i;
            const float4 pp = *(const float4*)&sm[C_B2 + m * LDF + tn * 4];
            *(float4*)&sm[C_B7 + m * LDF + tn * 4] =
                make_float4(acc[i][0] * pp.x, acc[i][1] * pp.y,
                            acc[i][2] * pp.z, acc[i][3] * pp.w);
        }
    }
    __syncthreads();

    mmNT_lds(sm, C_B1, C_B4, C_B2, 2, tid);
    mmNT_lds(sm, C_B7, C_B4, C_B6, 1, tid);
    __syncthreads();

    const int b_ = ch >> 4, h_ = ch & 15;
    const int tm = tid >> 4, tn = tid & 15;

    for (int vh = 0; vh < 2; ++vh) {
        stage32(sm, C_HV, Vp + ib,                  vh, tid);
        stage32(sm, C_HC, C0g + (size_t)bid * 4096, vh, tid);
        stage32(sm, C_HG, G0g + (size_t)bid * 4096, vh, tid);
        __syncthreads();
        {
            float acc[4][2] = {};
            mmNN32_acc<false>(sm, C_B1, C_HC, acc, tid);
            mmNN32_acc<false>(sm, C_B2, C_HV, acc, tid);
#pragma unroll
            for (int i = 0; i < 4; ++i) {
                sm[C_HK + (tm*4 + i) * LDH + tn*2 + 0] = acc[i][0];
                sm[C_HK + (tm*4 + i) * LDH + tn*2 + 1] = acc[i][1];
            }
        }
        __syncthreads();
        {
            float acc[4][2] = {};
            mmNN32_acc<false>(sm, C_B7, C_HC, acc, tid);
            mmNN32_acc<false>(sm, C_B6, C_HV, acc, tid);
            mmNN32_acc<true >(sm, C_B0, C_HG, acc, tid);
            mmNN32_acc<true >(sm, C_B3, C_HK, acc, tid);
#pragma unroll
            for (int i = 0; i < 4; ++i) {
                const int t = ck * 64 + tm * 4 + i;
                const size_t o = ((size_t)b_ * TT + t) * 1024 + h_ * 64 + vh * 32 + tn * 2;
                *(float2*)&Of[o] = make_float2(acc[i][0], acc[i][1]);
            }
        }
        __syncthreads();
    }
}

// ===========================================================================
// Fallback: round-1 sequential scan
// ===========================================================================
__global__ __launch_bounds__(256) void scan_kernel(
    const float* __restrict__ Q,  const float* __restrict__ Kv,
    const float* __restrict__ V,  const float* __restrict__ AK,
    const float* __restrict__ AC, float* __restrict__ Oflat)
{
    const int bh  = blockIdx.x;
    const int b_  = bh >> 4;
    const int h_  = bh & 15;
    const int tid = threadIdx.x;
    const int c   = tid >> 2;
    const int r4  = tid & 3;
    const int i0  = r4 * 16;

    __shared__ __align__(16) float vals[2][5][64];
    __shared__ __align__(16) float u_lds[64];

    const size_t base = (size_t)bh * TT * 64;
    const float* arrs[5] = {Q + base, Kv + base, V + base, AK + base, AC + base};

    float sk[16], cv[16], g[16];
#pragma unroll
    for (int r = 0; r < 16; ++r) { sk[r] = 0.f; cv[r] = 0.f; g[r] = 0.f; }

    const bool loader = (tid < 80);
    const int  larr = tid >> 4;
    const int  loff = (tid & 15) * 4;
    float4 pf[2];

    if (loader) {
        pf[0] = *(const float4*)(arrs[larr] + 0 * 64 + loff);
        pf[1] = *(const float4*)(arrs[larr] + 1 * 64 + loff);
        *(float4*)&vals[0][larr][loff] = pf[0];
    }
    __syncthreads();

    for (int t = 0; t < TT; ++t) {
        const int cur = t & 1;
        if (loader && (t + 2) < TT)
            pf[cur] = *(const float4*)(arrs[larr] + (size_t)(t + 2) * 64 + loff);

        float qv[16], kv[16], ak[16], ac[16];
#pragma unroll
        for (int r = 0; r < 16; r += 4) {
            *(float4*)&qv[r] = *(const float4*)&vals[cur][0][i0 + r];
            *(float4*)&kv[r] = *(const float4*)&vals[cur][1][i0 + r];
            *(float4*)&ak[r] = *(const float4*)&vals[cur][3][i0 + r];
            *(float4*)&ac[r] = *(const float4*)&vals[cur][4][i0 + r];
        }
        const float vc  = vals[cur][2][c];
        const float kc  = vals[cur][1][c];
        const float akc = vals[cur][3][c];

        float pk[4] = {0.f, 0.f, 0.f, 0.f};
#pragma unroll
        for (int r = 0; r < 16; ++r) {
            const float s = ac[r] * cv[r];
            pk[r & 3] = fmaf(kv[r], s, pk[r & 3]);
            cv[r] = fmaf(qv[r], vc, s);
        }
        float ktc = (pk[0] + pk[1]) + (pk[2] + pk[3]);
        ktc += __shfl_xor(ktc, 1);
        ktc += __shfl_xor(ktc, 2);

        float pu[4] = {0.f, 0.f, 0.f, 0.f};
        float pw[4] = {0.f, 0.f, 0.f, 0.f};
#pragma unroll
        for (int r = 0; r < 16; ++r) {
            g[r]  = fmaf(ak[r], g[r], kv[r] * ktc);
            sk[r] = fmaf(ak[r] * akc, sk[r], kv[r] * kc);
            pu[r & 3] = fmaf(qv[r], sk[r], pu[r & 3]);
            pw[r & 3] = fmaf(qv[r], g[r],  pw[r & 3]);
        }
        float u = (pu[0] + pu[1]) + (pu[2] + pu[3]);
        u += __shfl_xor(u, 1);
        u += __shfl_xor(u, 2);
        float w = (pw[0] + pw[1]) + (pw[2] + pw[3]);
        w += __shfl_xor(w, 1);
        w += __shfl_xor(w, 2);

        if (r4 == 0) u_lds[c] = u;
        __syncthreads();

        float po[4] = {0.f, 0.f, 0.f, 0.f};
#pragma unroll
        for (int r = 0; r < 16; r += 4) {
            const float4 uu = *(const float4*)&u_lds[i0 + r];
            po[0] = fmaf(uu.x, cv[r + 0], po[0]);
            po[1] = fmaf(uu.y, cv[r + 1], po[1]);
            po[2] = fmaf(uu.z, cv[r + 2], po[2]);
            po[3] = fmaf(uu.w, cv[r + 3], po[3]);
        }
        float o = (po[0] + po[1]) + (po[2] + po[3]);
        o += __shfl_xor(o, 1);
        o += __shfl_xor(o, 2);

        if (r4 == 0)
            Oflat[((size_t)b_ * TT + t) * 1024 + h_ * 64 + c] = o - w;

        if (loader && (t + 1) < TT)
            *(float4*)&vals[cur ^ 1][larr][loff] = pf[cur ^ 1];
        __syncthreads();
    }
}

// ===========================================================================
extern "C" void kernel_launch(void* const* d_in, const int* in_sizes, int n_in,
                              void* d_out, int out_size, void* d_ws, size_t ws_size,
                              hipStream_t stream)
{
    const float* x    = (const float*)d_in[0];
    const float* W_q  = (const float*)d_in[1];
    const float* W_k  = (const float*)d_in[2];
    const float* W_v  = (const float*)d_in[3];
    const float* Wg_K = (const float*)d_in[4];
    const float* bg_K = (const float*)d_in[5];
    const float* Wg_C = (const float*)d_in[6];
    const float* bg_C = (const float*)d_in[7];
    const float* W_o  = (const float*)d_in[8];

    float* ws = (float*)d_ws;
    const size_t S1  = (size_t)BB * NH * TT * 64;  // 8,388,608 floats
    const size_t WT1 = (size_t)1024 * 1024 / 2;    // 524,288 floats per bf16 Wt
    float* Qp = ws + 0 * S1;
    float* Kp = ws + 1 * S1;
    float* Vp = ws + 2 * S1;
    float* AK = ws + 3 * S1;
    float* AC = ws + 4 * S1;
    float* Of = ws + 5 * S1;

    dim3 blk(256);
    const size_t wsF = ws_size / 4;
    const bool mfma_ok = wsF >= 6 * S1 + 6 * WT1;

    if (mfma_ok) {
        bf16_t* WtO = (bf16_t*)(ws + 6 * S1);            // survives the scan
        bf16_t* WtP = (bf16_t*)(ws + 6 * S1 + WT1);      // 5 proj weights, aliased by chunk bufs

        wprep_kernel<<<dim3(16, 16, 6), blk, 0, stream>>>(
            W_q, W_k, W_v, Wg_K, Wg_C, W_o,
            WtP + 0 * 1048576, WtP + 1 * 1048576, WtP + 2 * 1048576,
            WtP + 3 * 1048576, WtP + 4 * 1048576, WtO);

        dim3 grid(BT / 128, 1024 / 128);
        gemm_bf16_kernel<<<grid, blk, 0, stream>>>(x, WtP + 0 * 1048576, nullptr, Qp, 0);
        gemm_bf16_kernel<<<grid, blk, 0, stream>>>(x, WtP + 1 * 1048576, nullptr, Kp, 0);
        gemm_bf16_kernel<<<grid, blk, 0, stream>>>(x, WtP + 2 * 1048576, nullptr, Vp, 0);
        gemm_bf16_kernel<<<grid, blk, 0, stream>>>(x, WtP + 3 * 1048576, bg_K,    AK, 1);
        gemm_bf16_kernel<<<grid, blk, 0, stream>>>(x, WtP + 4 * 1048576, bg_C,    AC, 1);

        // chunked scan; chunk buffers start right after WtO (alias WtP region)
        const size_t chunkBase = 6 * S1 + WT1;
        const size_t avail = wsF - chunkBase;
        int P = 0;
        for (int cand = 64; cand >= 4; cand >>= 1) {
            const size_t ex = (size_t)cand * 32 * 4096 * 4 + (size_t)cand * 32 * 64 * 2;
            if (avail >= ex) { P = cand; break; }
        }
        if (P > 0) {
            const size_t CS = (size_t)P * 32 * 4096;
            float* ASg  = ws + chunkBase;
            float* ACg  = ASg + CS;
            float* Mg   = ACg + CS;
            float* AGvg = Mg  + CS;
            float* DKg  = AGvg + CS;
            float* DCg  = DKg + (size_t)P * 32 * 64;
            for (int p0 = 0; p0 < 64; p0 += P) {
                chunk_sum_kernel<<<dim3(P * 32), blk, 0, stream>>>(
                    Qp, Kp, Vp, AK, AC, ASg, ACg, Mg, AGvg, DKg, DCg, p0);
                state_scan_kernel<<<dim3(P), blk, 0, stream>>>(
                    ASg, ACg, Mg, AGvg, DKg, DCg);
                chunk_out_kernel<<<dim3(P * 32), blk, 0, stream>>>(
                    Qp, Kp, Vp, AK, AC, ASg, ACg, AGvg, Of, p0);
            }
        } else {
            scan_kernel<<<dim3(64), blk, 0, stream>>>(Qp, Kp, Vp, AK, AC, Of);
        }

        gemm_bf16_kernel<<<grid, blk, 0, stream>>>(Of, WtO, nullptr, (float*)d_out, 2);
    } else {
        // old fp32 path (round-4)
        dim3 grid(BT / 128, 1024 / 128);
        gemm_kernel<<<grid, blk, 0, stream>>>(x, W_q,  nullptr, Qp, 0);
        gemm_kernel<<<grid, blk, 0, stream>>>(x, W_k,  nullptr, Kp, 0);
        gemm_kernel<<<grid, blk, 0, stream>>>(x, W_v,  nullptr, Vp, 0);
        gemm_kernel<<<grid, blk, 0, stream>>>(x, Wg_K, bg_K,    AK, 1);
        gemm_kernel<<<grid, blk, 0, stream>>>(x, Wg_C, bg_C,    AC, 1);

        const size_t availF = (wsF > 6 * S1) ? (wsF - 6 * S1) : 0;
        int P = 0;
        for (int cand = 64; cand >= 4; cand >>= 1) {
            const size_t ex = (size_t)cand * 32 * 4096 * 4 + (size_t)cand * 32 * 64 * 2;
            if (availF >= ex) { P = cand; break; }
        }
        if (P > 0) {
            const size_t CS = (size_t)P * 32 * 4096;
            float* ASg  = ws + 6 * S1;
            float* ACg  = ASg + CS;
            float* Mg   = ACg + CS;
            float* AGvg = Mg  + CS;
            float* DKg  = AGvg + CS;
            float* DCg  = DKg + (size_t)P * 32 * 64;
            for (int p0 = 0; p0 < 64; p0 += P) {
                chunk_sum_kernel<<<dim3(P * 32), blk, 0, stream>>>(
                    Qp, Kp, Vp, AK, AC, ASg, ACg, Mg, AGvg, DKg, DCg, p0);
                state_scan_kernel<<<dim3(P), blk, 0, stream>>>(
                    ASg, ACg, Mg, AGvg, DKg, DCg);
                chunk_out_kernel<<<dim3(P * 32), blk, 0, stream>>>(
                    Qp, Kp, Vp, AK, AC, ASg, ACg, AGvg, Of, p0);
            }
        } else {
            scan_kernel<<<dim3(64), blk, 0, stream>>>(Qp, Kp, Vp, AK, AC, Of);
        }
        gemm_kernel<<<grid, blk, 0, stream>>>(Of, W_o, nullptr, (float*)d_out, 2);
    }
}